// Round 3
// baseline (6164.082 us; speedup 1.0000x reference)
//
#include <hip/hip_runtime.h>
#include <hip/hip_bf16.h>

static constexpr int NN  = 100000;   // nodes
static constexpr int NE  = 400000;   // edges
static constexpr int NB  = 500;      // graphs
static constexpr int NS  = 75;       // seeds (K_SEEDS)
static constexpr int H   = 128;
static constexpr int NHD = 8;        // heads
static constexpr int DH  = 16;       // head dim
static constexpr float SCALE = 0.08838834764831845f; // 1/sqrt(128)

// ---------------- degree / edge-norm precompute ----------------
__global__ void k_fill1(float* __restrict__ d, int n){
    int i = blockIdx.x*256 + threadIdx.x;
    if (i < n) d[i] = 1.f;
}
__global__ void k_count(float* d, const int* __restrict__ dst, int e){
    int i = blockIdx.x*256 + threadIdx.x;
    if (i < e) atomicAdd(&d[dst[i]], 1.f);
}
__global__ void k_dinv(float* __restrict__ dinv, float* __restrict__ selfc, int n){
    int i = blockIdx.x*256 + threadIdx.x;
    if (i < n){ float r = rsqrtf(dinv[i]); dinv[i] = r; selfc[i] = r*r; }
}
__global__ void k_ce(float* __restrict__ ce, const float* __restrict__ dinv,
                     const int* __restrict__ src, const int* __restrict__ dst, int e){
    int i = blockIdx.x*256 + threadIdx.x;
    if (i < e) ce[i] = dinv[src[i]] * dinv[dst[i]];
}

// ---------------- generic GEMM: out[M,128] = x[M,K] @ W[128,K]^T ----------------
// optional bias, relu, and conv epilogue agg[m,c] = val * selfc[m].
// NOTE: agg may alias x (each block reads only its own output rows, all reads
// precede epilogue writes) -> x/out/agg deliberately NOT __restrict__.
__global__ __launch_bounds__(256) void gemm_k(const float* x, int M, int K,
    const float* __restrict__ W, const float* __restrict__ bias,
    float* out, float* agg, const float* __restrict__ selfc, int relu)
{
    __shared__ float xs[64][33];
    __shared__ __align__(16) float wt[32][132];
    const int tid  = threadIdx.x;
    const int row0 = blockIdx.x * 64;
    const int ct = tid & 31;   // cols ct*4 .. ct*4+3
    const int rt = tid >> 5;   // rows rt*8 .. rt*8+7
    float acc[8][4] = {};
    for (int k0 = 0; k0 < K; k0 += 32){
        #pragma unroll
        for (int i = 0; i < 8; ++i){            // 64x32 x-tile, coalesced
            int idx = tid + i*256;
            int r = idx >> 5, kk = idx & 31;
            int gr = row0 + r, gk = k0 + kk;
            float v = 0.f;
            if (gr < M && gk < K) v = x[(size_t)gr*K + gk];
            xs[r][kk] = v;
        }
        #pragma unroll
        for (int i = 0; i < 16; ++i){           // 128x32 W-chunk, transposed into LDS
            int idx = tid + i*256;
            int c = idx >> 5, kk = idx & 31;
            int gk = k0 + kk;
            wt[kk][c] = (gk < K) ? W[(size_t)c*K + gk] : 0.f;
        }
        __syncthreads();
        #pragma unroll
        for (int kk = 0; kk < 32; ++kk){
            const float4 wv = *(const float4*)&wt[kk][ct*4];
            #pragma unroll
            for (int i = 0; i < 8; ++i){
                float a = xs[rt*8 + i][kk];
                acc[i][0] += a * wv.x;
                acc[i][1] += a * wv.y;
                acc[i][2] += a * wv.z;
                acc[i][3] += a * wv.w;
            }
        }
        __syncthreads();
    }
    #pragma unroll
    for (int i = 0; i < 8; ++i){
        int r = row0 + rt*8 + i;
        if (r >= M) continue;
        float sc = agg ? selfc[r] : 0.f;
        #pragma unroll
        for (int j = 0; j < 4; ++j){
            int c = ct*4 + j;
            float v = acc[i][j];
            if (bias) v += bias[c];
            if (relu) v = fmaxf(v, 0.f);
            out[(size_t)r*H + c] = v;
            if (agg) agg[(size_t)r*H + c] = v * sc;
        }
    }
}

// ---------------- edge scatter: agg[dst] += h[src] * ce ----------------
__global__ __launch_bounds__(256) void k_scatter(const float* __restrict__ h,
    const int* __restrict__ src, const int* __restrict__ dst,
    const float* __restrict__ ce, float* agg, int e)
{
    int gid = blockIdx.x*256 + threadIdx.x;   // 32 lanes per edge
    int ed  = gid >> 5;
    if (ed >= e) return;
    int c4 = (gid & 31) << 2;
    int s = src[ed], d = dst[ed];
    float c = ce[ed];
    const float4 hv = *(const float4*)(h + (size_t)s*H + c4);
    float* ap = agg + (size_t)d*H + c4;
    atomicAdd(ap+0, hv.x*c);
    atomicAdd(ap+1, hv.y*c);
    atomicAdd(ap+2, hv.z*c);
    atomicAdd(ap+3, hv.w*c);
}

// ---------------- bias + optional relu (may be in-place) ----------------
__global__ void k_bias_act(const float* agg, const float* __restrict__ bias,
                           float* out, int M, int relu)
{
    int i = blockIdx.x*256 + threadIdx.x;
    if (i < M*H){
        int c = i & (H-1);
        float v = agg[i] + bias[c];
        if (relu) v = fmaxf(v, 0.f);
        out[i] = v;
    }
}

__global__ void k_add_ip(float* dst, const float* __restrict__ src, int n){
    int i = blockIdx.x*256 + threadIdx.x;
    if (i < n) dst[i] += src[i];
}

// ---------------- flash attention: out = Q + softmax(QK^T/sqrt(H)) V ----------------
// one block per (graph b, head h); Q broadcast over b when qbs==0.
__global__ __launch_bounds__(128) void k_attn(const float* __restrict__ Q, int qbs,
    const float* __restrict__ K, const float* __restrict__ V,
    float* __restrict__ out, int nq, int nk)
{
    int b = blockIdx.x >> 3, h = blockIdx.x & 7;
    __shared__ float Kh[200][16];
    __shared__ float Vh[200][16];
    int tid = threadIdx.x;
    for (int idx = tid; idx < nk*DH; idx += 128){
        int k = idx >> 4, d = idx & 15;
        size_t base = ((size_t)b*nk + k)*H + h*DH + d;
        Kh[k][d] = K[base];
        Vh[k][d] = V[base];
    }
    __syncthreads();
    if (tid < nq){
        const float* qp = Q + (size_t)b*qbs + (size_t)tid*H + h*DH;
        float Qr[DH];
        #pragma unroll
        for (int d = 0; d < DH; ++d) Qr[d] = qp[d] * SCALE;
        float m = -1e30f, l = 0.f, acc[DH];
        #pragma unroll
        for (int d = 0; d < DH; ++d) acc[d] = 0.f;
        for (int k = 0; k < nk; ++k){
            float s = 0.f;
            #pragma unroll
            for (int d = 0; d < DH; ++d) s += Qr[d] * Kh[k][d];
            float mn = fmaxf(m, s);
            float al = __expf(m - mn);
            float p  = __expf(s - mn);
            l = l*al + p;
            #pragma unroll
            for (int d = 0; d < DH; ++d) acc[d] = acc[d]*al + p*Vh[k][d];
            m = mn;
        }
        float inv = 1.f / l;
        size_t ob = ((size_t)b*nq + tid)*H + h*DH;
        #pragma unroll
        for (int d = 0; d < DH; ++d) out[ob + d] = qp[d] + acc[d]*inv;
    }
}

// ---------------- hERG: relu(herg_em[1,1280] @ W[128,1280]^T + b) ----------------
__global__ void k_herg(const float* __restrict__ em, const float* __restrict__ W,
                       const float* __restrict__ b, float* __restrict__ outv)
{
    __shared__ float e[1280];
    int t = threadIdx.x;
    for (int i = t; i < 1280; i += 128) e[i] = em[i];
    __syncthreads();
    float acc = 0.f;
    for (int k = 0; k < 1280; ++k) acc += e[k] * W[(size_t)t*1280 + k];
    outv[t] = fmaxf(acc + b[t], 0.f);
}

// ---------------- head MLP: concat -> relu fc -> relu fc -> sigmoid ----------------
__global__ __launch_bounds__(128) void k_final(const float* __restrict__ lin2out,
    const float* __restrict__ hergv,
    const float* __restrict__ hoW, const float* __restrict__ hob,
    const float* __restrict__ fcW, const float* __restrict__ fcb,
    const float* __restrict__ sW,  const float* __restrict__ sb,
    float* __restrict__ outp)
{
    int b = blockIdx.x, t = threadIdx.x;
    __shared__ float v256[256];
    __shared__ float tt[128];
    __shared__ float red[128];
    v256[t]       = lin2out[(size_t)b*H + t];
    v256[128 + t] = hergv[t];
    __syncthreads();
    float acc = 0.f;
    for (int k = 0; k < 256; ++k) acc += v256[k] * hoW[(size_t)t*256 + k];
    float tv = fmaxf(acc + hob[t], 0.f);
    tt[t] = tv;
    __syncthreads();
    acc = 0.f;
    for (int k = 0; k < 128; ++k) acc += tt[k] * fcW[(size_t)t*128 + k];
    float uv = fmaxf(acc + fcb[t], 0.f);
    red[t] = uv * sW[t];
    __syncthreads();
    for (int s = 64; s > 0; s >>= 1){
        if (t < s) red[t] += red[t + s];
        __syncthreads();
    }
    if (t == 0){
        float logit = red[0] + sb[0];
        outp[b] = 1.f / (1.f + expf(-logit));
    }
}

extern "C" void kernel_launch(void* const* d_in, const int* in_sizes, int n_in,
                              void* d_out, int out_size, void* d_ws, size_t ws_size,
                              hipStream_t stream)
{
    (void)in_sizes; (void)n_in; (void)out_size; (void)ws_size;
    const float* herg_em = (const float*)d_in[0];
    const float* x_in    = (const float*)d_in[1];
    const float* convW[4] = {(const float*)d_in[4], (const float*)d_in[6], (const float*)d_in[8], (const float*)d_in[10]};
    const float* convB[4] = {(const float*)d_in[5], (const float*)d_in[7], (const float*)d_in[9], (const float*)d_in[11]};
    const float* lin1W = (const float*)d_in[12]; const float* lin1b = (const float*)d_in[13];
    const float* lin2W = (const float*)d_in[14]; const float* lin2b = (const float*)d_in[15];
    const float* S1    = (const float*)d_in[16];
    const float* p1fqW = (const float*)d_in[17]; const float* p1fqb = (const float*)d_in[18];
    const float* p1kW  = (const float*)d_in[19]; const float* p1kb  = (const float*)d_in[20];
    const float* p1vW  = (const float*)d_in[21]; const float* p1vb  = (const float*)d_in[22];
    const float* p1foW = (const float*)d_in[23]; const float* p1fob = (const float*)d_in[24];
    const float* sfqW  = (const float*)d_in[25]; const float* sfqb  = (const float*)d_in[26];
    const float* skW   = (const float*)d_in[27]; const float* skb   = (const float*)d_in[28];
    const float* svW   = (const float*)d_in[29]; const float* svb   = (const float*)d_in[30];
    const float* sfoW  = (const float*)d_in[31]; const float* sfob  = (const float*)d_in[32];
    // dict order: pma2 weights come BEFORE S2 (the setup loop covers pma1/sab/pma2)
    const float* p2fqW = (const float*)d_in[33]; const float* p2fqb = (const float*)d_in[34];
    const float* p2kW  = (const float*)d_in[35]; const float* p2kb  = (const float*)d_in[36];
    const float* p2vW  = (const float*)d_in[37]; const float* p2vb  = (const float*)d_in[38];
    const float* p2foW = (const float*)d_in[39]; const float* p2fob = (const float*)d_in[40];
    const float* S2    = (const float*)d_in[41];
    const float* hlW   = (const float*)d_in[42]; const float* hlb   = (const float*)d_in[43];
    const float* hoW   = (const float*)d_in[44]; const float* hob   = (const float*)d_in[45];
    const float* fcW   = (const float*)d_in[46]; const float* fcb   = (const float*)d_in[47];
    const float* sW    = (const float*)d_in[48]; const float* sb    = (const float*)d_in[49];
    const int*  ei    = (const int*)d_in[50];
    const int*  esrc  = ei;
    const int*  edst  = ei + NE;
    float* outp = (float*)d_out;

    // -------- workspace layout (floats); total ~156.4 MB --------
    float* F      = (float*)d_ws;
    float* dinv   = F;                 // NN
    float* selfc  = F + 100000;        // NN
    float* ce     = F + 200000;        // NE
    float* q0     = F + 600000;        // 75*128
    float* q2     = F + 609600;        // 128
    float* hergv  = F + 609728;        // 128
    float* l2out  = F + 609856;        // 500*128
    float* big0   = F + 700000;        // NN*H
    float* big1   = big0 + (size_t)NN*H;
    float* big2   = big1 + (size_t)NN*H;

    const int gN   = (NN + 255)/256;
    const int gE   = (NE + 255)/256;
    const int gNH  = (NN*H + 255)/256;       // 50000
    const int gSc  = (NE*32 + 255)/256;      // 50000
    const int gRow = (NN + 63)/64;           // 1563
    const int gXb  = (NB*NS + 63)/64;        // 586 (37500 rows)
    const int nXb  = NB*NS*H;                // 4.8M

    // ---- degree / norms ----
    k_fill1<<<gN, 256, 0, stream>>>(dinv, NN);
    k_count<<<gE, 256, 0, stream>>>(dinv, edst, NE);
    k_dinv <<<gN, 256, 0, stream>>>(dinv, selfc, NN);
    k_ce   <<<gE, 256, 0, stream>>>(ce, dinv, esrc, edst, NE);

    // ---- seed-Q projections (graph-independent) + hERG vector ----
    gemm_k<<<(NS+63)/64, 256, 0, stream>>>(S1, NS, H, p1fqW, p1fqb, q0, nullptr, nullptr, 0);
    gemm_k<<<1, 256, 0, stream>>>(S2, 1, H, p2fqW, p2fqb, q2, nullptr, nullptr, 0);
    k_herg<<<1, 128, 0, stream>>>(herg_em, hlW, hlb, hergv);

    // ---- conv0 (K=37) ----
    gemm_k<<<gRow, 256, 0, stream>>>(x_in, NN, 37, convW[0], nullptr, big1, big0, selfc, 0);
    k_scatter <<<gSc, 256, 0, stream>>>(big1, esrc, edst, ce, big0, NE);
    k_bias_act<<<gNH, 256, 0, stream>>>(big0, convB[0], big0, NN, 1);
    // ---- conv1..3 (agg aliases x: safe, per-block row ownership) ----
    for (int l = 1; l < 4; ++l){
        gemm_k<<<gRow, 256, 0, stream>>>(big0, NN, H, convW[l], nullptr, big1, big0, selfc, 0);
        k_scatter <<<gSc, 256, 0, stream>>>(big1, esrc, edst, ce, big0, NE);
        k_bias_act<<<gNH, 256, 0, stream>>>(big0, convB[l], big0, NN, 1);
    }
    // ---- lin1 -> hx in big1 ----
    gemm_k<<<gRow, 256, 0, stream>>>(big0, NN, H, lin1W, lin1b, big1, nullptr, nullptr, 0);
    // ---- pma1 V = gcn(hx) -> big0 ----
    gemm_k<<<gRow, 256, 0, stream>>>(big1, NN, H, p1vW, nullptr, big2, big0, selfc, 0);
    k_scatter <<<gSc, 256, 0, stream>>>(big2, esrc, edst, ce, big0, NE);
    k_bias_act<<<gNH, 256, 0, stream>>>(big0, p1vb, big0, NN, 0);
    // ---- pma1 K = gcn(hx) -> big1 (agg aliases hx in-place) ----
    gemm_k<<<gRow, 256, 0, stream>>>(big1, NN, H, p1kW, nullptr, big2, big1, selfc, 0);
    k_scatter <<<gSc, 256, 0, stream>>>(big2, esrc, edst, ce, big1, NE);
    k_bias_act<<<gNH, 256, 0, stream>>>(big1, p1kb, big1, NN, 0);
    // ---- GMPool_G attention: xb1 -> big2 ----
    k_attn<<<NB*NHD, 128, 0, stream>>>(q0, 0, big1, big0, big2, NS, 200);
    gemm_k<<<gXb, 256, 0, stream>>>(big2, NB*NS, H, p1foW, p1fob, big0, nullptr, nullptr, 1);
    k_add_ip<<<(nXb+255)/256, 256, 0, stream>>>(big2, big0, nXb);
    // ---- SAB ----
    gemm_k<<<gXb, 256, 0, stream>>>(big2, NB*NS, H, sfqW, sfqb, big0, nullptr, nullptr, 0);        // Qs
    gemm_k<<<gXb, 256, 0, stream>>>(big2, NB*NS, H, skW,  skb,  big0 + nXb, nullptr, nullptr, 0);  // Ks
    gemm_k<<<gXb, 256, 0, stream>>>(big2, NB*NS, H, svW,  svb,  big1, nullptr, nullptr, 0);        // Vs
    k_attn<<<NB*NHD, 128, 0, stream>>>(big0, NS*H, big0 + nXb, big1, big2, NS, NS);
    gemm_k<<<gXb, 256, 0, stream>>>(big2, NB*NS, H, sfoW, sfob, big0, nullptr, nullptr, 1);
    k_add_ip<<<(nXb+255)/256, 256, 0, stream>>>(big2, big0, nXb);
    // ---- GMPool_I ----
    gemm_k<<<gXb, 256, 0, stream>>>(big2, NB*NS, H, p2kW, p2kb, big0, nullptr, nullptr, 0);  // Kp
    gemm_k<<<gXb, 256, 0, stream>>>(big2, NB*NS, H, p2vW, p2vb, big1, nullptr, nullptr, 0);  // Vp
    k_attn<<<NB*NHD, 128, 0, stream>>>(q2, 0, big0, big1, big2, 1, NS);                      // xb3 [500,128]
    gemm_k<<<(NB+63)/64, 256, 0, stream>>>(big2, NB, H, p2foW, p2fob, big0, nullptr, nullptr, 1);
    k_add_ip<<<(NB*H+255)/256, 256, 0, stream>>>(big2, big0, NB*H);
    // ---- lin2 ----
    gemm_k<<<(NB+63)/64, 256, 0, stream>>>(big2, NB, H, lin2W, lin2b, l2out, nullptr, nullptr, 0);
    // ---- head ----
    k_final<<<NB, 128, 0, stream>>>(l2out, hergv, hoW, hob, fcW, fcb, sW, sb, outp);
}

// Round 4
// 2268.074 us; speedup vs baseline: 2.7178x; 2.7178x over previous
//
#include <hip/hip_runtime.h>
#include <hip/hip_bf16.h>

static constexpr int NN  = 100000;   // nodes
static constexpr int NE  = 400000;   // edges
static constexpr int NB  = 500;      // graphs
static constexpr int NS  = 75;       // seeds (K_SEEDS)
static constexpr int H   = 128;
static constexpr int DH  = 16;       // head dim
static constexpr float SCALE = 0.08838834764831845f; // 1/sqrt(128)

// ================= CSR build =================
__global__ void k_zero_i(int* __restrict__ p, int n){
    int i = blockIdx.x*256 + threadIdx.x;
    if (i < n) p[i] = 0;
}
__global__ void k_hist(int* counts, const int* __restrict__ dst, int e){
    int i = blockIdx.x*256 + threadIdx.x;
    if (i < e) atomicAdd(&counts[dst[i]], 1);
}
__global__ void k_norms(const int* __restrict__ counts, float* __restrict__ dinv,
                        float* __restrict__ selfc, int n){
    int i = blockIdx.x*256 + threadIdx.x;
    if (i < n){
        float r = rsqrtf(1.f + (float)counts[i]);
        dinv[i] = r; selfc[i] = r*r;
    }
}
// block-wise exclusive scan of counts -> row_start (partial), block totals
__global__ __launch_bounds__(256) void k_scan1(const int* __restrict__ counts,
    int* __restrict__ row_start, int* __restrict__ blockSums, int n){
    __shared__ int s[256];
    int t = threadIdx.x, i = blockIdx.x*256 + t;
    int v = (i < n) ? counts[i] : 0;
    s[t] = v; __syncthreads();
    #pragma unroll
    for (int off = 1; off < 256; off <<= 1){
        int add = (t >= off) ? s[t-off] : 0;
        __syncthreads();
        s[t] += add;
        __syncthreads();
    }
    if (i < n) row_start[i] = s[t] - v;
    if (t == 255) blockSums[blockIdx.x] = s[255];
}
// single-block exclusive scan of block sums (nb <= 512)
__global__ __launch_bounds__(512) void k_scan2(const int* __restrict__ blockSums,
    int* __restrict__ blockOff, int nb){
    __shared__ int s[512];
    int t = threadIdx.x;
    int v = (t < nb) ? blockSums[t] : 0;
    s[t] = v; __syncthreads();
    #pragma unroll
    for (int off = 1; off < 512; off <<= 1){
        int add = (t >= off) ? s[t-off] : 0;
        __syncthreads();
        s[t] += add;
        __syncthreads();
    }
    blockOff[t] = s[t] - v;
}
__global__ void k_scan3(int* __restrict__ row_start, int* __restrict__ cursor,
                        const int* __restrict__ blockOff, int n, int total){
    int i = blockIdx.x*256 + threadIdx.x;
    if (i < n){
        int v = row_start[i] + blockOff[i >> 8];
        row_start[i] = v; cursor[i] = v;
    }
    if (i == 0) row_start[n] = total;
}
__global__ void k_fillcsr(const int* __restrict__ src, const int* __restrict__ dst,
    const float* __restrict__ dinv, int* cursor,
    int* __restrict__ srcs_s, float* __restrict__ ce_s, int e){
    int i = blockIdx.x*256 + threadIdx.x;
    if (i < e){
        int d = dst[i], s = src[i];
        int p = atomicAdd(&cursor[d], 1);
        srcs_s[p] = s;
        ce_s[p] = dinv[s] * dinv[d];
    }
}

// ================= CSR gather aggregation: out = Â x =================
// one 64-lane group per dst node; lane handles features {lane, lane+64}
__global__ __launch_bounds__(256) void k_gather128(const float* __restrict__ x,
    const int* __restrict__ row_start, const int* __restrict__ srcs,
    const float* __restrict__ ces, const float* __restrict__ selfc,
    float* __restrict__ out, int n)
{
    int gid = blockIdx.x*256 + threadIdx.x;
    int node = gid >> 6, lane = gid & 63;
    if (node >= n) return;
    size_t base = (size_t)node*H;
    float sc = selfc[node];
    float a0 = sc * x[base + lane];
    float a1 = sc * x[base + lane + 64];
    int e1 = row_start[node+1];
    for (int e = row_start[node]; e < e1; ++e){
        int s = srcs[e];
        float c = ces[e];
        size_t sb = (size_t)s*H;
        a0 += c * x[sb + lane];
        a1 += c * x[sb + lane + 64];
    }
    out[base + lane]      = a0;
    out[base + lane + 64] = a1;
}
// 37-feature variant (raw input features, pre-conv0)
__global__ __launch_bounds__(256) void k_gather37(const float* __restrict__ x,
    const int* __restrict__ row_start, const int* __restrict__ srcs,
    const float* __restrict__ ces, const float* __restrict__ selfc,
    float* __restrict__ out, int n)
{
    int gid = blockIdx.x*256 + threadIdx.x;
    int node = gid >> 6, lane = gid & 63;
    if (node >= n || lane >= 37) return;
    size_t base = (size_t)node*37;
    float a0 = selfc[node] * x[base + lane];
    int e1 = row_start[node+1];
    for (int e = row_start[node]; e < e1; ++e){
        a0 += ces[e] * x[(size_t)srcs[e]*37 + lane];
    }
    out[base + lane] = a0;
}

// ========== GEMM: out[M,128] = resid + act(x[M,K] @ W[128,K]^T + b) ==========
__global__ __launch_bounds__(256) void gemm_k(const float* x, int M, int K,
    const float* __restrict__ W, const float* __restrict__ bias,
    float* out, const float* resid, int relu)
{
    __shared__ float xs[64][33];
    __shared__ __align__(16) float wt[32][132];
    const int tid  = threadIdx.x;
    const int row0 = blockIdx.x * 64;
    const int ct = tid & 31;   // cols ct*4 .. ct*4+3
    const int rt = tid >> 5;   // rows rt*8 .. rt*8+7
    float acc[8][4] = {};
    for (int k0 = 0; k0 < K; k0 += 32){
        #pragma unroll
        for (int i = 0; i < 8; ++i){            // 64x32 x-tile, coalesced
            int idx = tid + i*256;
            int r = idx >> 5, kk = idx & 31;
            int gr = row0 + r, gk = k0 + kk;
            float v = 0.f;
            if (gr < M && gk < K) v = x[(size_t)gr*K + gk];
            xs[r][kk] = v;
        }
        #pragma unroll
        for (int i = 0; i < 16; ++i){           // 128x32 W-chunk, transposed into LDS
            int idx = tid + i*256;
            int c = idx >> 5, kk = idx & 31;
            int gk = k0 + kk;
            wt[kk][c] = (gk < K) ? W[(size_t)c*K + gk] : 0.f;
        }
        __syncthreads();
        #pragma unroll
        for (int kk = 0; kk < 32; ++kk){
            const float4 wv = *(const float4*)&wt[kk][ct*4];
            #pragma unroll
            for (int i = 0; i < 8; ++i){
                float a = xs[rt*8 + i][kk];
                acc[i][0] += a * wv.x;
                acc[i][1] += a * wv.y;
                acc[i][2] += a * wv.z;
                acc[i][3] += a * wv.w;
            }
        }
        __syncthreads();
    }
    #pragma unroll
    for (int i = 0; i < 8; ++i){
        int r = row0 + rt*8 + i;
        if (r >= M) continue;
        #pragma unroll
        for (int j = 0; j < 4; ++j){
            int c = ct*4 + j;
            float v = acc[i][j];
            if (bias) v += bias[c];
            if (relu) v = fmaxf(v, 0.f);
            if (resid) v += resid[(size_t)r*H + c];
            out[(size_t)r*H + c] = v;
        }
    }
}

// ====== flash attention: out = Q + softmax(QK^T/sqrt(H)) V  (per graph,head) ======
__global__ __launch_bounds__(128) void k_attn(const float* __restrict__ Q, int qbs,
    const float* __restrict__ K, const float* __restrict__ V,
    float* __restrict__ out, int nq, int nk)
{
    int b = blockIdx.x >> 3, h = blockIdx.x & 7;
    __shared__ float Kh[200][16];
    __shared__ float Vh[200][16];
    int tid = threadIdx.x;
    for (int idx = tid; idx < nk*DH; idx += 128){
        int k = idx >> 4, d = idx & 15;
        size_t base = ((size_t)b*nk + k)*H + h*DH + d;
        Kh[k][d] = K[base];
        Vh[k][d] = V[base];
    }
    __syncthreads();
    if (tid < nq){
        const float* qp = Q + (size_t)b*qbs + (size_t)tid*H + h*DH;
        float Qr[DH];
        #pragma unroll
        for (int d = 0; d < DH; ++d) Qr[d] = qp[d] * SCALE;
        float m = -1e30f, l = 0.f, acc[DH];
        #pragma unroll
        for (int d = 0; d < DH; ++d) acc[d] = 0.f;
        for (int k = 0; k < nk; ++k){
            float s = 0.f;
            #pragma unroll
            for (int d = 0; d < DH; ++d) s += Qr[d] * Kh[k][d];
            float mn = fmaxf(m, s);
            float al = __expf(m - mn);
            float p  = __expf(s - mn);
            l = l*al + p;
            #pragma unroll
            for (int d = 0; d < DH; ++d) acc[d] = acc[d]*al + p*Vh[k][d];
            m = mn;
        }
        float inv = 1.f / l;
        size_t ob = ((size_t)b*nq + tid)*H + h*DH;
        #pragma unroll
        for (int d = 0; d < DH; ++d) out[ob + d] = qp[d] + acc[d]*inv;
    }
}

// ---------------- hERG: relu(herg_em[1,1280] @ W[128,1280]^T + b) ----------------
__global__ void k_herg(const float* __restrict__ em, const float* __restrict__ W,
                       const float* __restrict__ b, float* __restrict__ outv)
{
    __shared__ float e[1280];
    int t = threadIdx.x;
    for (int i = t; i < 1280; i += 128) e[i] = em[i];
    __syncthreads();
    float acc = 0.f;
    for (int k = 0; k < 1280; ++k) acc += e[k] * W[(size_t)t*1280 + k];
    outv[t] = fmaxf(acc + b[t], 0.f);
}

// ---------------- head MLP: concat -> relu fc -> relu fc -> sigmoid ----------------
__global__ __launch_bounds__(128) void k_final(const float* __restrict__ lin2out,
    const float* __restrict__ hergv,
    const float* __restrict__ hoW, const float* __restrict__ hob,
    const float* __restrict__ fcW, const float* __restrict__ fcb,
    const float* __restrict__ sW,  const float* __restrict__ sb,
    float* __restrict__ outp)
{
    int b = blockIdx.x, t = threadIdx.x;
    __shared__ float v256[256];
    __shared__ float tt[128];
    __shared__ float red[128];
    v256[t]       = lin2out[(size_t)b*H + t];
    v256[128 + t] = hergv[t];
    __syncthreads();
    float acc = 0.f;
    for (int k = 0; k < 256; ++k) acc += v256[k] * hoW[(size_t)t*256 + k];
    tt[t] = fmaxf(acc + hob[t], 0.f);
    __syncthreads();
    acc = 0.f;
    for (int k = 0; k < 128; ++k) acc += tt[k] * fcW[(size_t)t*128 + k];
    float uv = fmaxf(acc + fcb[t], 0.f);
    red[t] = uv * sW[t];
    __syncthreads();
    for (int s = 64; s > 0; s >>= 1){
        if (t < s) red[t] += red[t + s];
        __syncthreads();
    }
    if (t == 0){
        float logit = red[0] + sb[0];
        outp[b] = 1.f / (1.f + expf(-logit));
    }
}

extern "C" void kernel_launch(void* const* d_in, const int* in_sizes, int n_in,
                              void* d_out, int out_size, void* d_ws, size_t ws_size,
                              hipStream_t stream)
{
    (void)in_sizes; (void)n_in; (void)out_size; (void)ws_size;
    const float* herg_em = (const float*)d_in[0];
    const float* x_in    = (const float*)d_in[1];
    const float* convW[4] = {(const float*)d_in[4], (const float*)d_in[6], (const float*)d_in[8], (const float*)d_in[10]};
    const float* convB[4] = {(const float*)d_in[5], (const float*)d_in[7], (const float*)d_in[9], (const float*)d_in[11]};
    const float* lin1W = (const float*)d_in[12]; const float* lin1b = (const float*)d_in[13];
    const float* lin2W = (const float*)d_in[14]; const float* lin2b = (const float*)d_in[15];
    const float* S1    = (const float*)d_in[16];
    const float* p1fqW = (const float*)d_in[17]; const float* p1fqb = (const float*)d_in[18];
    const float* p1kW  = (const float*)d_in[19]; const float* p1kb  = (const float*)d_in[20];
    const float* p1vW  = (const float*)d_in[21]; const float* p1vb  = (const float*)d_in[22];
    const float* p1foW = (const float*)d_in[23]; const float* p1fob = (const float*)d_in[24];
    const float* sfqW  = (const float*)d_in[25]; const float* sfqb  = (const float*)d_in[26];
    const float* skW   = (const float*)d_in[27]; const float* skb   = (const float*)d_in[28];
    const float* svW   = (const float*)d_in[29]; const float* svb   = (const float*)d_in[30];
    const float* sfoW  = (const float*)d_in[31]; const float* sfob  = (const float*)d_in[32];
    const float* p2fqW = (const float*)d_in[33]; const float* p2fqb = (const float*)d_in[34];
    const float* p2kW  = (const float*)d_in[35]; const float* p2kb  = (const float*)d_in[36];
    const float* p2vW  = (const float*)d_in[37]; const float* p2vb  = (const float*)d_in[38];
    const float* p2foW = (const float*)d_in[39]; const float* p2fob = (const float*)d_in[40];
    const float* S2    = (const float*)d_in[41];
    const float* hlW   = (const float*)d_in[42]; const float* hlb   = (const float*)d_in[43];
    const float* hoW   = (const float*)d_in[44]; const float* hob   = (const float*)d_in[45];
    const float* fcW   = (const float*)d_in[46]; const float* fcb   = (const float*)d_in[47];
    const float* sW    = (const float*)d_in[48]; const float* sb    = (const float*)d_in[49];
    const int*  ei    = (const int*)d_in[50];
    const int*  esrc  = ei;
    const int*  edst  = ei + NE;
    float* outp = (float*)d_out;

    // -------- workspace layout (floats/ints); total ~159.2 MB --------
    float* F       = (float*)d_ws;
    float* dinv    = F;                    // 100000
    float* selfc   = F + 100000;           // 100000
    int*   counts  = (int*)(F + 200000);   // 100000
    int*   cursor  = (int*)(F + 300000);   // 100000
    int*   row_st  = (int*)(F + 400000);   // 100001
    int*   bSums   = (int*)(F + 500032);   // 512
    int*   bOff    = (int*)(F + 500544);   // 512
    float* q0      = F + 501056;           // 9600
    float* q2      = F + 510656;           // 128
    float* hergv   = F + 510784;           // 128
    float* l2out   = F + 510912;           // 64000
    int*   srcs_s  = (int*)(F + 574912);   // 400000
    float* ce_s    = F + 974912;           // 400000
    float* big0    = F + 1400000;          // NN*H
    float* big1    = big0 + (size_t)NN*H;
    float* big2    = big1 + (size_t)NN*H;

    const int gN   = (NN + 255)/256;       // 391
    const int gE   = (NE + 255)/256;
    const int gG   = (NN*64 + 255)/256;    // 25000 (gather)
    const int gRow = (NN + 63)/64;         // 1563
    const int gXb  = (NB*NS + 63)/64;      // 586 (37500 rows)
    const int nXb  = NB*NS*H;              // 4.8M

    // ---- CSR build (no float atomics anywhere downstream) ----
    k_zero_i<<<gN, 256, 0, stream>>>(counts, NN);
    k_hist  <<<gE, 256, 0, stream>>>(counts, edst, NE);
    k_norms <<<gN, 256, 0, stream>>>(counts, dinv, selfc, NN);
    k_scan1 <<<gN, 256, 0, stream>>>(counts, row_st, bSums, NN);
    k_scan2 <<<1, 512, 0, stream>>>(bSums, bOff, gN);
    k_scan3 <<<gN, 256, 0, stream>>>(row_st, cursor, bOff, NN, NE);
    k_fillcsr<<<gE, 256, 0, stream>>>(esrc, edst, dinv, cursor, srcs_s, ce_s, NE);

    // ---- seed-Q projections (graph-independent) + hERG vector ----
    gemm_k<<<(NS+63)/64, 256, 0, stream>>>(S1, NS, H, p1fqW, p1fqb, q0, nullptr, 0);
    gemm_k<<<1, 256, 0, stream>>>(S2, 1, H, p2fqW, p2fqb, q2, nullptr, 0);
    k_herg<<<1, 128, 0, stream>>>(herg_em, hlW, hlb, hergv);

    // ---- conv0: aggregate raw 37-dim features FIRST, then GEMM (Â(xW)= (Âx)W) ----
    k_gather37<<<gG, 256, 0, stream>>>(x_in, row_st, srcs_s, ce_s, selfc, big2, NN);
    gemm_k<<<gRow, 256, 0, stream>>>(big2, NN, 37, convW[0], convB[0], big0, nullptr, 1);
    // ---- conv1..3: aggregate then GEMM(bias+relu) ----
    for (int l = 1; l < 4; ++l){
        k_gather128<<<gG, 256, 0, stream>>>(big0, row_st, srcs_s, ce_s, selfc, big1, NN);
        gemm_k<<<gRow, 256, 0, stream>>>(big1, NN, H, convW[l], convB[l], big0, nullptr, 1);
    }
    // ---- lin1 -> hx in big1 ----
    gemm_k<<<gRow, 256, 0, stream>>>(big0, NN, H, lin1W, lin1b, big1, nullptr, 0);
    // ---- shared aggregation for pma1 K and V: zx = Â hx ----
    k_gather128<<<gG, 256, 0, stream>>>(big1, row_st, srcs_s, ce_s, selfc, big2, NN);
    gemm_k<<<gRow, 256, 0, stream>>>(big2, NN, H, p1kW, p1kb, big1, nullptr, 0);   // K
    gemm_k<<<gRow, 256, 0, stream>>>(big2, NN, H, p1vW, p1vb, big0, nullptr, 0);   // V
    // ---- GMPool_G attention ----
    k_attn<<<NB*8, 128, 0, stream>>>(q0, 0, big1, big0, big2, NS, 200);
    gemm_k<<<gXb, 256, 0, stream>>>(big2, NB*NS, H, p1foW, p1fob, big0, big2, 1);  // xb1 = attn + relu(attn@W+b)
    // ---- SAB ----
    gemm_k<<<gXb, 256, 0, stream>>>(big0, NB*NS, H, sfqW, sfqb, big1, nullptr, 0);        // Qs
    gemm_k<<<gXb, 256, 0, stream>>>(big0, NB*NS, H, skW,  skb,  big1 + nXb, nullptr, 0);  // Ks
    gemm_k<<<gXb, 256, 0, stream>>>(big0, NB*NS, H, svW,  svb,  big2, nullptr, 0);        // Vs
    k_attn<<<NB*8, 128, 0, stream>>>(big1, NS*H, big1 + nXb, big2, big2 + nXb, NS, NS);
    gemm_k<<<gXb, 256, 0, stream>>>(big2 + nXb, NB*NS, H, sfoW, sfob, big0, big2 + nXb, 1); // xb2
    // ---- GMPool_I ----
    gemm_k<<<gXb, 256, 0, stream>>>(big0, NB*NS, H, p2kW, p2kb, big1, nullptr, 0);        // Kp
    gemm_k<<<gXb, 256, 0, stream>>>(big0, NB*NS, H, p2vW, p2vb, big1 + nXb, nullptr, 0);  // Vp
    k_attn<<<NB*8, 128, 0, stream>>>(q2, 0, big1, big1 + nXb, big2, 1, NS);               // [500,128]
    gemm_k<<<(NB+63)/64, 256, 0, stream>>>(big2, NB, H, p2foW, p2fob, big0, big2, 1);     // xb3
    // ---- lin2 ----
    gemm_k<<<(NB+63)/64, 256, 0, stream>>>(big0, NB, H, lin2W, lin2b, l2out, nullptr, 0);
    // ---- head ----
    k_final<<<NB, 128, 0, stream>>>(l2out, hergv, hoW, hob, fcW, fcb, sW, sb, outp);
}

// Round 5
// 1328.369 us; speedup vs baseline: 4.6403x; 1.7074x over previous
//
#include <hip/hip_runtime.h>
#include <hip/hip_bf16.h>

typedef unsigned short ushort_t;
typedef unsigned int uint_t;
typedef __attribute__((ext_vector_type(8))) short short8;
typedef __attribute__((ext_vector_type(4))) float float4v;

static constexpr int NN  = 100000;   // nodes
static constexpr int NE  = 400000;   // edges
static constexpr int NB  = 500;      // graphs
static constexpr int NS  = 75;       // seeds
static constexpr int H   = 128;
static constexpr float SCALE = 0.08838834764831845f; // 1/sqrt(128)

union U32 { uint_t u; float f; };
__device__ __forceinline__ float bf2f(ushort_t b){ U32 t; t.u = ((uint_t)b) << 16; return t.f; }
__device__ __forceinline__ ushort_t f2bf(float f){
    U32 t; t.f = f;
    uint_t r = t.u + 0x7fffu + ((t.u >> 16) & 1u);   // RNE
    return (ushort_t)(r >> 16);
}

// ================= CSR build =================
__global__ void k_zero_i(int* __restrict__ p, int n){
    int i = blockIdx.x*256 + threadIdx.x;
    if (i < n) p[i] = 0;
}
__global__ void k_hist(int* counts, const int* __restrict__ dst, int e){
    int i = blockIdx.x*256 + threadIdx.x;
    if (i < e) atomicAdd(&counts[dst[i]], 1);
}
__global__ void k_norms(const int* __restrict__ counts, float* __restrict__ dinv,
                        float* __restrict__ selfc, int n){
    int i = blockIdx.x*256 + threadIdx.x;
    if (i < n){
        float r = rsqrtf(1.f + (float)counts[i]);
        dinv[i] = r; selfc[i] = r*r;
    }
}
__global__ __launch_bounds__(256) void k_scan1(const int* __restrict__ counts,
    int* __restrict__ row_start, int* __restrict__ blockSums, int n){
    __shared__ int s[256];
    int t = threadIdx.x, i = blockIdx.x*256 + t;
    int v = (i < n) ? counts[i] : 0;
    s[t] = v; __syncthreads();
    #pragma unroll
    for (int off = 1; off < 256; off <<= 1){
        int add = (t >= off) ? s[t-off] : 0;
        __syncthreads();
        s[t] += add;
        __syncthreads();
    }
    if (i < n) row_start[i] = s[t] - v;
    if (t == 255) blockSums[blockIdx.x] = s[255];
}
__global__ __launch_bounds__(512) void k_scan2(const int* __restrict__ blockSums,
    int* __restrict__ blockOff, int nb){
    __shared__ int s[512];
    int t = threadIdx.x;
    int v = (t < nb) ? blockSums[t] : 0;
    s[t] = v; __syncthreads();
    #pragma unroll
    for (int off = 1; off < 512; off <<= 1){
        int add = (t >= off) ? s[t-off] : 0;
        __syncthreads();
        s[t] += add;
        __syncthreads();
    }
    blockOff[t] = s[t] - v;
}
__global__ void k_scan3(int* __restrict__ row_start, int* __restrict__ cursor,
                        const int* __restrict__ blockOff, int n, int total){
    int i = blockIdx.x*256 + threadIdx.x;
    if (i < n){
        int v = row_start[i] + blockOff[i >> 8];
        row_start[i] = v; cursor[i] = v;
    }
    if (i == 0) row_start[n] = total;
}
__global__ void k_fillcsr(const int* __restrict__ src, const int* __restrict__ dst,
    const float* __restrict__ dinv, int* cursor,
    int* __restrict__ srcs_s, float* __restrict__ ce_s, int e){
    int i = blockIdx.x*256 + threadIdx.x;
    if (i < e){
        int d = dst[i], s = src[i];
        int p = atomicAdd(&cursor[d], 1);
        srcs_s[p] = s;
        ce_s[p] = dinv[s] * dinv[d];
    }
}

// ================= weight conversion =================
struct WPtrs { const float* p[17]; };
__global__ void k_cvtW(WPtrs wp, ushort_t* __restrict__ dst){
    int i = blockIdx.x*256 + threadIdx.x;   // 17*16384 total
    int idx = i >> 14, off = i & 16383;
    dst[i] = f2bf(wp.p[idx][off]);
}
__global__ void k_cvtW0(const float* __restrict__ src, ushort_t* __restrict__ dst){
    int i = blockIdx.x*256 + threadIdx.x;   // 128*64
    int r = i >> 6, c = i & 63;
    dst[i] = (c < 37) ? f2bf(src[r*37 + c]) : (ushort_t)0;
}
__global__ void k_cvt(const float* __restrict__ s, ushort_t* __restrict__ d, int n){
    int i = blockIdx.x*256 + threadIdx.x;
    if (i < n) d[i] = f2bf(s[i]);
}

// ========== CSR gather (bf16): out = Â x, 64 lanes/node, 2 cols/lane ==========
__global__ __launch_bounds__(256) void k_gather128b(const ushort_t* __restrict__ x,
    const int* __restrict__ row_start, const int* __restrict__ srcs,
    const float* __restrict__ ces, const float* __restrict__ selfc,
    ushort_t* __restrict__ out, int n)
{
    int gid = blockIdx.x*256 + threadIdx.x;
    int node = gid >> 6, lane = gid & 63;
    if (node >= n) return;
    size_t base = (size_t)node*H + lane*2;
    float sc = selfc[node];
    uint_t u = *(const uint_t*)(x + base);
    float a0 = sc * bf2f((ushort_t)(u & 0xffff));
    float a1 = sc * bf2f((ushort_t)(u >> 16));
    int e1 = row_start[node+1];
    for (int e = row_start[node]; e < e1; ++e){
        int s = srcs[e]; float c = ces[e];
        uint_t w = *(const uint_t*)(x + (size_t)s*H + lane*2);
        a0 += c * bf2f((ushort_t)(w & 0xffff));
        a1 += c * bf2f((ushort_t)(w >> 16));
    }
    uint_t o = (uint_t)f2bf(a0) | ((uint_t)f2bf(a1) << 16);
    *(uint_t*)(out + base) = o;
}
// raw 37-dim features -> padded 64-wide bf16
__global__ __launch_bounds__(256) void k_gather37b(const float* __restrict__ x,
    const int* __restrict__ row_start, const int* __restrict__ srcs,
    const float* __restrict__ ces, const float* __restrict__ selfc,
    ushort_t* __restrict__ out, int n)
{
    int gid = blockIdx.x*256 + threadIdx.x;
    int node = gid >> 6, lane = gid & 63;
    if (node >= n) return;
    float a0 = 0.f;
    if (lane < 37){
        a0 = selfc[node] * x[(size_t)node*37 + lane];
        int e1 = row_start[node+1];
        for (int e = row_start[node]; e < e1; ++e)
            a0 += ces[e] * x[(size_t)srcs[e]*37 + lane];
    }
    out[(size_t)node*64 + lane] = f2bf(a0);
}

// ========== MFMA GEMM: out[M,128] = resid + act(x[M,Ks] @ W[128,Ks]^T + b) ==========
// A/B frags: direct 16B loads (A[m=lane&15][k=quad*8+j]); C/D: col=lane&15,row=quad*4+reg.
__global__ __launch_bounds__(256) void gemm_mfma(
    const ushort_t* __restrict__ x, int M, int Ks,
    const ushort_t* __restrict__ W,       // [128][Ks] bf16
    const float* __restrict__ bias,       // fp32 or null
    ushort_t* out, const ushort_t* resid, int relu, float* out32)
{
    int tid  = threadIdx.x;
    int wid  = tid >> 6;
    int lane = tid & 63;
    int l15  = lane & 15, quad = lane >> 4;
    int row0 = blockIdx.x*64 + wid*16;
    int ar   = row0 + l15; if (ar > M-1) ar = M-1;   // clamp (stores guarded)
    const short* xr = (const short*)(x + (size_t)ar*Ks) + quad*8;
    float4v acc[8];
    #pragma unroll
    for (int i = 0; i < 8; ++i) acc[i] = (float4v)0.f;
    for (int k0 = 0; k0 < Ks; k0 += 32){
        short8 a = *(const short8*)(xr + k0);
        #pragma unroll
        for (int nt = 0; nt < 8; ++nt){
            const short* wr = (const short*)(W + (size_t)(nt*16 + l15)*Ks) + k0 + quad*8;
            short8 b = *(const short8*)wr;
            acc[nt] = __builtin_amdgcn_mfma_f32_16x16x32_bf16(a, b, acc[nt], 0, 0, 0);
        }
    }
    #pragma unroll
    for (int nt = 0; nt < 8; ++nt){
        int c = nt*16 + l15;
        float bv = bias ? bias[c] : 0.f;
        #pragma unroll
        for (int reg = 0; reg < 4; ++reg){
            int r = row0 + quad*4 + reg;
            if (r >= M) continue;
            float v = acc[nt][reg] + bv;
            if (relu) v = fmaxf(v, 0.f);
            if (resid) v += bf2f(resid[(size_t)r*H + c]);
            if (out32) out32[(size_t)r*H + c] = v;
            else       out[(size_t)r*H + c] = f2bf(v);
        }
    }
}

// ====== split-K flash attention: out = Q + softmax(QK^T/sqrt(H)) V ======
// one block per (graph,head); 256 threads; thread t -> (q=t/nsplit, s=t%nsplit)
__global__ __launch_bounds__(256) void k_attn2(
    const ushort_t* __restrict__ Q, int qbs,             // bf16, per-graph stride qbs (0=broadcast)
    const ushort_t* __restrict__ K, const ushort_t* __restrict__ V,  // [B,nk,128] bf16
    ushort_t* __restrict__ out,                          // [B,nq,128] bf16
    int nq, int nk, int nsplit)
{
    int b = blockIdx.x >> 3, h = blockIdx.x & 7;
    __shared__ uint_t KhU[200*8];
    __shared__ uint_t VhU[200*8];
    __shared__ float sm[256], sl[256];
    __shared__ float sacc[256][16];
    int tid = threadIdx.x;
    const uint_t* Kg = (const uint_t*)(K + (size_t)b*nk*H + h*16);
    const uint_t* Vg = (const uint_t*)(V + (size_t)b*nk*H + h*16);
    for (int idx = tid; idx < nk*8; idx += 256){
        int k = idx >> 3, d = idx & 7;
        KhU[idx] = Kg[(size_t)k*64 + d];
        VhU[idx] = Vg[(size_t)k*64 + d];
    }
    __syncthreads();
    int q = tid / nsplit, s = tid - q*nsplit;
    float m = -1e30f, l = 0.f, acc[16];
    #pragma unroll
    for (int d = 0; d < 16; ++d) acc[d] = 0.f;
    const ushort_t* Qp = nullptr;
    if (q < nq){
        Qp = Q + (size_t)b*qbs + (size_t)q*H + h*16;
        float Qr[16];
        #pragma unroll
        for (int d = 0; d < 16; ++d) Qr[d] = bf2f(Qp[d]) * SCALE;
        int len = (nk + nsplit - 1) / nsplit;
        int k0 = s*len, k1 = min(nk, k0 + len);
        for (int k = k0; k < k1; ++k){
            float sc = 0.f;
            #pragma unroll
            for (int i = 0; i < 8; ++i){
                uint_t u = KhU[k*8 + i];
                sc += Qr[2*i]   * bf2f((ushort_t)(u & 0xffff));
                sc += Qr[2*i+1] * bf2f((ushort_t)(u >> 16));
            }
            float mn = fmaxf(m, sc);
            float al = __expf(m - mn);
            float p  = __expf(sc - mn);
            l = l*al + p;
            #pragma unroll
            for (int i = 0; i < 8; ++i){
                uint_t u = VhU[k*8 + i];
                acc[2*i]   = acc[2*i]  *al + p * bf2f((ushort_t)(u & 0xffff));
                acc[2*i+1] = acc[2*i+1]*al + p * bf2f((ushort_t)(u >> 16));
            }
            m = mn;
        }
    }
    sm[tid] = m; sl[tid] = l;
    #pragma unroll
    for (int d = 0; d < 16; ++d) sacc[tid][d] = acc[d];
    __syncthreads();
    if (q < nq && s == 0){
        for (int j = 1; j < nsplit; ++j){
            int t2 = tid + j;
            float mj = sm[t2], lj = sl[t2];
            float M2 = fmaxf(m, mj);
            float a0 = __expf(m - M2), a1 = __expf(mj - M2);
            l = l*a0 + lj*a1;
            #pragma unroll
            for (int d = 0; d < 16; ++d) acc[d] = acc[d]*a0 + sacc[t2][d]*a1;
            m = M2;
        }
        float inv = 1.f / l;
        ushort_t* op = out + ((size_t)b*nq + q)*H + h*16;
        #pragma unroll
        for (int d = 0; d < 16; ++d) op[d] = f2bf(bf2f(Qp[d]) + acc[d]*inv);
    }
}

// ---------------- hERG (fp32): relu(herg_em[1,1280] @ W[128,1280]^T + b) ----------------
__global__ void k_herg(const float* __restrict__ em, const float* __restrict__ W,
                       const float* __restrict__ b, float* __restrict__ outv)
{
    __shared__ float e[1280];
    int t = threadIdx.x;
    for (int i = t; i < 1280; i += 128) e[i] = em[i];
    __syncthreads();
    float acc = 0.f;
    for (int k = 0; k < 1280; ++k) acc += e[k] * W[(size_t)t*1280 + k];
    outv[t] = fmaxf(acc + b[t], 0.f);
}

// ---------------- head MLP (fp32) ----------------
__global__ __launch_bounds__(128) void k_final(const float* __restrict__ lin2out,
    const float* __restrict__ hergv,
    const float* __restrict__ hoW, const float* __restrict__ hob,
    const float* __restrict__ fcW, const float* __restrict__ fcb,
    const float* __restrict__ sW,  const float* __restrict__ sb,
    float* __restrict__ outp)
{
    int b = blockIdx.x, t = threadIdx.x;
    __shared__ float v256[256];
    __shared__ float tt[128];
    __shared__ float red[128];
    v256[t]       = lin2out[(size_t)b*H + t];
    v256[128 + t] = hergv[t];
    __syncthreads();
    float acc = 0.f;
    for (int k = 0; k < 256; ++k) acc += v256[k] * hoW[(size_t)t*256 + k];
    tt[t] = fmaxf(acc + hob[t], 0.f);
    __syncthreads();
    acc = 0.f;
    for (int k = 0; k < 128; ++k) acc += tt[k] * fcW[(size_t)t*128 + k];
    float uv = fmaxf(acc + fcb[t], 0.f);
    red[t] = uv * sW[t];
    __syncthreads();
    for (int s = 64; s > 0; s >>= 1){
        if (t < s) red[t] += red[t + s];
        __syncthreads();
    }
    if (t == 0){
        float logit = red[0] + sb[0];
        outp[b] = 1.f / (1.f + expf(-logit));
    }
}

extern "C" void kernel_launch(void* const* d_in, const int* in_sizes, int n_in,
                              void* d_out, int out_size, void* d_ws, size_t ws_size,
                              hipStream_t stream)
{
    (void)in_sizes; (void)n_in; (void)out_size; (void)ws_size;
    const float* herg_em = (const float*)d_in[0];
    const float* x_in    = (const float*)d_in[1];
    const float* convW[4] = {(const float*)d_in[4], (const float*)d_in[6], (const float*)d_in[8], (const float*)d_in[10]};
    const float* convB[4] = {(const float*)d_in[5], (const float*)d_in[7], (const float*)d_in[9], (const float*)d_in[11]};
    const float* lin1W = (const float*)d_in[12]; const float* lin1b = (const float*)d_in[13];
    const float* lin2W = (const float*)d_in[14]; const float* lin2b = (const float*)d_in[15];
    const float* S1    = (const float*)d_in[16];
    const float* p1fqW = (const float*)d_in[17]; const float* p1fqb = (const float*)d_in[18];
    const float* p1kW  = (const float*)d_in[19]; const float* p1kb  = (const float*)d_in[20];
    const float* p1vW  = (const float*)d_in[21]; const float* p1vb  = (const float*)d_in[22];
    const float* p1foW = (const float*)d_in[23]; const float* p1fob = (const float*)d_in[24];
    const float* sfqW  = (const float*)d_in[25]; const float* sfqb  = (const float*)d_in[26];
    const float* skW   = (const float*)d_in[27]; const float* skb   = (const float*)d_in[28];
    const float* svW   = (const float*)d_in[29]; const float* svb   = (const float*)d_in[30];
    const float* sfoW  = (const float*)d_in[31]; const float* sfob  = (const float*)d_in[32];
    const float* p2fqW = (const float*)d_in[33]; const float* p2fqb = (const float*)d_in[34];
    const float* p2kW  = (const float*)d_in[35]; const float* p2kb  = (const float*)d_in[36];
    const float* p2vW  = (const float*)d_in[37]; const float* p2vb  = (const float*)d_in[38];
    const float* p2foW = (const float*)d_in[39]; const float* p2fob = (const float*)d_in[40];
    const float* S2    = (const float*)d_in[41];
    const float* hlW   = (const float*)d_in[42]; const float* hlb   = (const float*)d_in[43];
    const float* hoW   = (const float*)d_in[44]; const float* hob   = (const float*)d_in[45];
    const float* fcW   = (const float*)d_in[46]; const float* fcb   = (const float*)d_in[47];
    const float* sW    = (const float*)d_in[48]; const float* sb    = (const float*)d_in[49];
    const int*  ei    = (const int*)d_in[50];
    const int*  esrc  = ei;
    const int*  edst  = ei + NE;
    float* outp = (float*)d_out;

    // -------- workspace layout (byte offsets, all 16B-aligned) --------
    char* WS = (char*)d_ws;
    int*   counts = (int*)(WS + 0);            // 100000
    int*   cursor = (int*)(WS + 400384);       // 100000
    int*   row_st = (int*)(WS + 800768);       // 100001
    int*   bSums  = (int*)(WS + 1201152);      // 512
    int*   bOff   = (int*)(WS + 1203200);      // 512
    float* dinv   = (float*)(WS + 1205248);    // 100000
    float* selfc  = (float*)(WS + 1605632);    // 100000
    int*   srcs_s = (int*)(WS + 2005632);      // 400000
    float* ce_s   = (float*)(WS + 3605632);    // 400000
    ushort_t* wbf = (ushort_t*)(WS + 5205632); // 17*16384
    ushort_t* w0bf= (ushort_t*)(WS + 5762688); // 128*64
    ushort_t* s1bf= (ushort_t*)(WS + 5779072); // 9600
    ushort_t* s2bf= (ushort_t*)(WS + 5798272); // 128
    ushort_t* q0  = (ushort_t*)(WS + 5798528); // 9600
    ushort_t* q2  = (ushort_t*)(WS + 5817728); // 128
    float* hergv  = (float*)(WS + 5817984);    // 128
    float* l2out  = (float*)(WS + 5818496);    // 64000
    ushort_t* x37 = (ushort_t*)(WS + 6074496); // NN*64
    ushort_t* b0  = (ushort_t*)(WS + 18874496);// NN*128
    ushort_t* b1  = (ushort_t*)(WS + 44474496);
    ushort_t* b2  = (ushort_t*)(WS + 70074496);
    ushort_t* xA  = (ushort_t*)(WS + 95674496);   // 37504*128
    ushort_t* xB  = (ushort_t*)(WS + 105275520);
    ushort_t* xQ  = (ushort_t*)(WS + 114876544);
    ushort_t* xK  = (ushort_t*)(WS + 124477568);
    ushort_t* xV  = (ushort_t*)(WS + 134078592);  // end ~143.7 MB

    const int gN   = (NN + 255)/256;       // 391
    const int gE   = (NE + 255)/256;       // 1563
    const int gG   = (NN*64)/256;          // 25000
    const int gRow = (NN + 63)/64;         // 1563
    const int gXb  = (NB*NS + 63)/64;      // 586

    // ---- CSR build ----
    k_zero_i<<<gN, 256, 0, stream>>>(counts, NN);
    k_hist  <<<gE, 256, 0, stream>>>(counts, edst, NE);
    k_norms <<<gN, 256, 0, stream>>>(counts, dinv, selfc, NN);
    k_scan1 <<<gN, 256, 0, stream>>>(counts, row_st, bSums, NN);
    k_scan2 <<<1, 512, 0, stream>>>(bSums, bOff, gN);
    k_scan3 <<<gN, 256, 0, stream>>>(row_st, cursor, bOff, NN, NE);
    k_fillcsr<<<gE, 256, 0, stream>>>(esrc, edst, dinv, cursor, srcs_s, ce_s, NE);

    // ---- weight conversions ----
    WPtrs wp;
    wp.p[0]=convW[1]; wp.p[1]=convW[2]; wp.p[2]=convW[3]; wp.p[3]=lin1W; wp.p[4]=lin2W;
    wp.p[5]=p1kW; wp.p[6]=p1vW; wp.p[7]=p1foW;
    wp.p[8]=sfqW; wp.p[9]=skW; wp.p[10]=svW; wp.p[11]=sfoW;
    wp.p[12]=p2kW; wp.p[13]=p2vW; wp.p[14]=p2foW; wp.p[15]=p1fqW; wp.p[16]=p2fqW;
    k_cvtW <<<17*64, 256, 0, stream>>>(wp, wbf);
    k_cvtW0<<<32, 256, 0, stream>>>(convW[0], w0bf);
    k_cvt  <<<38, 256, 0, stream>>>(S1, s1bf, NS*H);
    k_cvt  <<<1, 256, 0, stream>>>(S2, s2bf, H);

    // ---- seed-Q projections + hERG ----
    gemm_mfma<<<2, 256, 0, stream>>>(s1bf, NS, H, wbf + (size_t)15*16384, p1fqb, q0, nullptr, 0, nullptr);
    gemm_mfma<<<1, 256, 0, stream>>>(s2bf, 1,  H, wbf + (size_t)16*16384, p2fqb, q2, nullptr, 0, nullptr);
    k_herg<<<1, 128, 0, stream>>>(herg_em, hlW, hlb, hergv);

    // ---- conv0: aggregate raw 37-dim, then MFMA GEMM (padded K=64) ----
    k_gather37b<<<gG, 256, 0, stream>>>(x_in, row_st, srcs_s, ce_s, selfc, x37, NN);
    gemm_mfma<<<gRow, 256, 0, stream>>>(x37, NN, 64, w0bf, convB[0], b0, nullptr, 1, nullptr);
    // ---- conv1..3 ----
    for (int l = 1; l < 4; ++l){
        k_gather128b<<<gG, 256, 0, stream>>>(b0, row_st, srcs_s, ce_s, selfc, b1, NN);
        gemm_mfma<<<gRow, 256, 0, stream>>>(b1, NN, H, wbf + (size_t)(l-1)*16384, convB[l], b0, nullptr, 1, nullptr);
    }
    // ---- lin1 -> hx in b1 ----
    gemm_mfma<<<gRow, 256, 0, stream>>>(b0, NN, H, wbf + (size_t)3*16384, lin1b, b1, nullptr, 0, nullptr);
    // ---- shared aggregation: zx = Â hx -> b2; K -> b1, V -> b0 ----
    k_gather128b<<<gG, 256, 0, stream>>>(b1, row_st, srcs_s, ce_s, selfc, b2, NN);
    gemm_mfma<<<gRow, 256, 0, stream>>>(b2, NN, H, wbf + (size_t)5*16384, p1kb, b1, nullptr, 0, nullptr);
    gemm_mfma<<<gRow, 256, 0, stream>>>(b2, NN, H, wbf + (size_t)6*16384, p1vb, b0, nullptr, 0, nullptr);
    // ---- GMPool_G ----
    k_attn2<<<NB*8, 256, 0, stream>>>(q0, 0, b1, b0, xA, NS, 200, 3);
    gemm_mfma<<<gXb, 256, 0, stream>>>(xA, NB*NS, H, wbf + (size_t)7*16384, p1fob, xB, xA, 1, nullptr);
    // ---- SAB ----
    gemm_mfma<<<gXb, 256, 0, stream>>>(xB, NB*NS, H, wbf + (size_t)8*16384, sfqb, xQ, nullptr, 0, nullptr);
    gemm_mfma<<<gXb, 256, 0, stream>>>(xB, NB*NS, H, wbf + (size_t)9*16384, skb,  xK, nullptr, 0, nullptr);
    gemm_mfma<<<gXb, 256, 0, stream>>>(xB, NB*NS, H, wbf + (size_t)10*16384, svb, xV, nullptr, 0, nullptr);
    k_attn2<<<NB*8, 256, 0, stream>>>(xQ, NS*H, xK, xV, xA, NS, NS, 3);
    gemm_mfma<<<gXb, 256, 0, stream>>>(xA, NB*NS, H, wbf + (size_t)11*16384, sfob, xB, xA, 1, nullptr);
    // ---- GMPool_I ----
    gemm_mfma<<<gXb, 256, 0, stream>>>(xB, NB*NS, H, wbf + (size_t)12*16384, p2kb, xK, nullptr, 0, nullptr);
    gemm_mfma<<<gXb, 256, 0, stream>>>(xB, NB*NS, H, wbf + (size_t)13*16384, p2vb, xV, nullptr, 0, nullptr);
    k_attn2<<<NB*8, 256, 0, stream>>>(q2, 0, xK, xV, xA, 1, NS, 75);
    gemm_mfma<<<(NB+63)/64, 256, 0, stream>>>(xA, NB, H, wbf + (size_t)14*16384, p2fob, xB, xA, 1, nullptr);
    // ---- lin2 (fp32 out) ----
    gemm_mfma<<<(NB+63)/64, 256, 0, stream>>>(xB, NB, H, wbf + (size_t)4*16384, lin2b, nullptr, nullptr, 0, l2out);
    // ---- head ----
    k_final<<<NB, 128, 0, stream>>>(l2out, hergv, hoW, hob, fcW, fcb, sW, sb, outp);
}

// Round 6
// 1027.076 us; speedup vs baseline: 6.0016x; 1.2934x over previous
//
#include <hip/hip_runtime.h>
#include <hip/hip_bf16.h>

typedef unsigned short ushort_t;
typedef unsigned int uint_t;
typedef __attribute__((ext_vector_type(8))) short short8;
typedef __attribute__((ext_vector_type(4))) float float4v;

static constexpr int NN  = 100000;   // nodes
static constexpr int NE  = 400000;   // edges
static constexpr int NB  = 500;      // graphs
static constexpr int NS  = 75;       // seeds
static constexpr int H   = 128;
static constexpr float SCALE = 0.08838834764831845f; // 1/sqrt(128)

union U32 { uint_t u; float f; };
__device__ __forceinline__ float bf2f(ushort_t b){ U32 t; t.u = ((uint_t)b) << 16; return t.f; }
__device__ __forceinline__ ushort_t f2bf(float f){
    U32 t; t.f = f;
    uint_t r = t.u + 0x7fffu + ((t.u >> 16) & 1u);   // RNE
    return (ushort_t)(r >> 16);
}

// ================= CSR build =================
__global__ void k_zero_i(int* __restrict__ p, int n){
    int i = blockIdx.x*256 + threadIdx.x;
    if (i < n) p[i] = 0;
}
__global__ void k_hist(int* counts, const int* __restrict__ dst, int e){
    int i = blockIdx.x*256 + threadIdx.x;
    if (i < e) atomicAdd(&counts[dst[i]], 1);
}
__global__ void k_norms(const int* __restrict__ counts, float* __restrict__ dinv,
                        float* __restrict__ selfc, int n){
    int i = blockIdx.x*256 + threadIdx.x;
    if (i < n){
        float r = rsqrtf(1.f + (float)counts[i]);
        dinv[i] = r; selfc[i] = r*r;
    }
}
__global__ __launch_bounds__(256) void k_scan1(const int* __restrict__ counts,
    int* __restrict__ row_start, int* __restrict__ blockSums, int n){
    __shared__ int s[256];
    int t = threadIdx.x, i = blockIdx.x*256 + t;
    int v = (i < n) ? counts[i] : 0;
    s[t] = v; __syncthreads();
    #pragma unroll
    for (int off = 1; off < 256; off <<= 1){
        int add = (t >= off) ? s[t-off] : 0;
        __syncthreads();
        s[t] += add;
        __syncthreads();
    }
    if (i < n) row_start[i] = s[t] - v;
    if (t == 255) blockSums[blockIdx.x] = s[255];
}
__global__ __launch_bounds__(512) void k_scan2(const int* __restrict__ blockSums,
    int* __restrict__ blockOff, int nb){
    __shared__ int s[512];
    int t = threadIdx.x;
    int v = (t < nb) ? blockSums[t] : 0;
    s[t] = v; __syncthreads();
    #pragma unroll
    for (int off = 1; off < 512; off <<= 1){
        int add = (t >= off) ? s[t-off] : 0;
        __syncthreads();
        s[t] += add;
        __syncthreads();
    }
    blockOff[t] = s[t] - v;
}
__global__ void k_scan3(int* __restrict__ row_start, int* __restrict__ cursor,
                        const int* __restrict__ blockOff, int n, int total){
    int i = blockIdx.x*256 + threadIdx.x;
    if (i < n){
        int v = row_start[i] + blockOff[i >> 8];
        row_start[i] = v; cursor[i] = v;
    }
    if (i == 0) row_start[n] = total;
}
__global__ void k_fillcsr(const int* __restrict__ src, const int* __restrict__ dst,
    const float* __restrict__ dinv, int* cursor,
    int* __restrict__ srcs_s, float* __restrict__ ce_s, int e){
    int i = blockIdx.x*256 + threadIdx.x;
    if (i < e){
        int d = dst[i], s = src[i];
        int p = atomicAdd(&cursor[d], 1);
        srcs_s[p] = s;
        ce_s[p] = dinv[s] * dinv[d];
    }
}

// ================= weight conversion =================
struct WPtrs { const float* p[17]; };
__global__ void k_cvtW(WPtrs wp, ushort_t* __restrict__ dst){
    int i = blockIdx.x*256 + threadIdx.x;   // 17*16384 total
    int idx = i >> 14, off = i & 16383;
    dst[i] = f2bf(wp.p[idx][off]);
}
__global__ void k_cvtW0(const float* __restrict__ src, ushort_t* __restrict__ dst){
    int i = blockIdx.x*256 + threadIdx.x;   // 128*64
    int r = i >> 6, c = i & 63;
    dst[i] = (c < 37) ? f2bf(src[r*37 + c]) : (ushort_t)0;
}
__global__ void k_cvt(const float* __restrict__ s, ushort_t* __restrict__ d, int n){
    int i = blockIdx.x*256 + threadIdx.x;
    if (i < n) d[i] = f2bf(s[i]);
}

// raw 37-dim features -> aggregated, padded 64-wide bf16
__global__ __launch_bounds__(256) void k_gather37b(const float* __restrict__ x,
    const int* __restrict__ row_start, const int* __restrict__ srcs,
    const float* __restrict__ ces, const float* __restrict__ selfc,
    ushort_t* __restrict__ out, int n)
{
    int gid = blockIdx.x*256 + threadIdx.x;
    int node = gid >> 6, lane = gid & 63;
    if (node >= n) return;
    float a0 = 0.f;
    if (lane < 37){
        a0 = selfc[node] * x[(size_t)node*37 + lane];
        int e1 = row_start[node+1];
        for (int e = row_start[node]; e < e1; ++e)
            a0 += ces[e] * x[(size_t)srcs[e]*37 + lane];
    }
    out[(size_t)node*64 + lane] = f2bf(a0);
}

// ========== MFMA GEMM: out[M,128] = resid + act(x[M,Ks] @ W[128,Ks]^T + b) ==========
__global__ __launch_bounds__(256) void gemm_mfma(
    const ushort_t* __restrict__ x, int M, int Ks,
    const ushort_t* __restrict__ W,       // [128][Ks] bf16
    const float* __restrict__ bias,       // fp32 or null
    ushort_t* out, const ushort_t* resid, int relu, float* out32)
{
    int tid  = threadIdx.x;
    int wid  = tid >> 6;
    int lane = tid & 63;
    int l15  = lane & 15, quad = lane >> 4;
    int row0 = blockIdx.x*64 + wid*16;
    int ar   = row0 + l15; if (ar > M-1) ar = M-1;   // clamp (stores guarded)
    const short* xr = (const short*)(x + (size_t)ar*Ks) + quad*8;
    float4v acc[8];
    #pragma unroll
    for (int i = 0; i < 8; ++i) acc[i] = (float4v)0.f;
    for (int k0 = 0; k0 < Ks; k0 += 32){
        short8 a = *(const short8*)(xr + k0);
        #pragma unroll
        for (int nt = 0; nt < 8; ++nt){
            const short* wr = (const short*)(W + (size_t)(nt*16 + l15)*Ks) + k0 + quad*8;
            short8 b = *(const short8*)wr;
            acc[nt] = __builtin_amdgcn_mfma_f32_16x16x32_bf16(a, b, acc[nt], 0, 0, 0);
        }
    }
    #pragma unroll
    for (int nt = 0; nt < 8; ++nt){
        int c = nt*16 + l15;
        float bv = bias ? bias[c] : 0.f;
        #pragma unroll
        for (int reg = 0; reg < 4; ++reg){
            int r = row0 + quad*4 + reg;
            if (r >= M) continue;
            float v = acc[nt][reg] + bv;
            if (relu) v = fmaxf(v, 0.f);
            if (resid) v += bf2f(resid[(size_t)r*H + c]);
            if (out32) out32[(size_t)r*H + c] = v;
            else       out[(size_t)r*H + c] = f2bf(v);
        }
    }
}

// ========== fused gather + MFMA GEMM ==========
// block = 64 nodes; gather agg rows into LDS (bf16), then GEMM vs W.
// NOUT=8: one 128-col output. NOUT=16: W has 256 rows; cols 0..127 -> out0, 128..255 -> out1.
template<int NOUT>
__global__ __launch_bounds__(256) void k_conv_fused(
    const ushort_t* __restrict__ x,
    const int* __restrict__ row_st, const int* __restrict__ srcs,
    const float* __restrict__ ces, const float* __restrict__ selfc,
    const ushort_t* __restrict__ W, const float* __restrict__ bias0,
    const float* __restrict__ bias1,
    ushort_t* __restrict__ out0, ushort_t* __restrict__ out1, int relu)
{
    __shared__ ushort_t As[64][136];     // stride 136 -> conflict-light, 16B aligned
    int tid = threadIdx.x;
    int node = tid >> 2, qq = tid & 3;   // 4 threads/node, 32 cols each
    int g = blockIdx.x*64 + node;
    float acc[32];
    if (g < NN){
        const uint_t* xr = (const uint_t*)(x + (size_t)g*H + qq*32);
        float sc = selfc[g];
        #pragma unroll
        for (int i = 0; i < 16; ++i){
            uint_t u = xr[i];
            acc[2*i]   = sc * bf2f((ushort_t)(u & 0xffff));
            acc[2*i+1] = sc * bf2f((ushort_t)(u >> 16));
        }
        int e1 = row_st[g+1];
        for (int e = row_st[g]; e < e1; ++e){
            int s = srcs[e]; float c = ces[e];
            const uint_t* sr = (const uint_t*)(x + (size_t)s*H + qq*32);
            #pragma unroll
            for (int i = 0; i < 16; ++i){
                uint_t u = sr[i];
                acc[2*i]   += c * bf2f((ushort_t)(u & 0xffff));
                acc[2*i+1] += c * bf2f((ushort_t)(u >> 16));
            }
        }
    } else {
        #pragma unroll
        for (int i = 0; i < 32; ++i) acc[i] = 0.f;
    }
    uint_t* dst = (uint_t*)&As[node][qq*32];
    #pragma unroll
    for (int i = 0; i < 16; ++i)
        dst[i] = (uint_t)f2bf(acc[2*i]) | ((uint_t)f2bf(acc[2*i+1]) << 16);
    __syncthreads();
    // GEMM from LDS
    int w = tid >> 6, lane = tid & 63;
    int l15 = lane & 15, quad = lane >> 4;
    float4v o[NOUT];
    #pragma unroll
    for (int nt = 0; nt < NOUT; ++nt) o[nt] = (float4v)0.f;
    #pragma unroll
    for (int kc = 0; kc < 4; ++kc){
        short8 a = *(const short8*)(&As[w*16 + l15][kc*32 + quad*8]);
        #pragma unroll
        for (int nt = 0; nt < NOUT; ++nt){
            const short8* wp = (const short8*)(W + (size_t)(nt*16 + l15)*H + kc*32 + quad*8);
            o[nt] = __builtin_amdgcn_mfma_f32_16x16x32_bf16(a, *wp, o[nt], 0, 0, 0);
        }
    }
    #pragma unroll
    for (int nt = 0; nt < NOUT; ++nt){
        int c = nt*16 + l15;
        float bv = (NOUT == 16 && nt >= 8) ? bias1[c - 128] : bias0[c];
        #pragma unroll
        for (int reg = 0; reg < 4; ++reg){
            int r = blockIdx.x*64 + w*16 + quad*4 + reg;
            if (r >= NN) continue;
            float v = o[nt][reg] + bv;
            if (relu) v = fmaxf(v, 0.f);
            if (NOUT == 16 && nt >= 8) out1[(size_t)r*H + (c - 128)] = f2bf(v);
            else                       out0[(size_t)r*H + c] = f2bf(v);
        }
    }
}

// ========== MFMA flash attention: out = Q + softmax(QK^T/sqrt(128)) V ==========
// block = (graph, head-pair); 4 waves: wave -> (head = pair*2 + (w>>1), q-half = w&1)
template<int NK>
__global__ __launch_bounds__(256) void k_attn_mfma(
    const ushort_t* __restrict__ Q, int qbs,
    const ushort_t* __restrict__ K, const ushort_t* __restrict__ V,
    ushort_t* __restrict__ out, int nq)
{
    constexpr int NKT = (NK + 15) / 16;     // S k-tiles
    constexpr int NKC = (NK + 31) / 32;     // PV k-chunks
    __shared__ ushort_t Ks[2][208][24];     // [head][key][d]   (stride 24: 16B aligned)
    __shared__ ushort_t Vs[2][16][232];     // [head][d][key]   (transposed)
    __shared__ ushort_t Ps[4][16][232];     // per-wave P tile  [q][key]
    int b = blockIdx.x >> 2, hp = blockIdx.x & 3;
    int h0 = hp*2;
    int tid = threadIdx.x;
    // zero P (covers PV pad cols)
    {
        uint_t* p = (uint_t*)&Ps[0][0][0];
        for (int i = tid; i < 4*16*232/2; i += 256) p[i] = 0;
    }
    // stage K: per key, the 2 heads' 32 cols are 64B contiguous
    const ushort_t* Kb = K + (size_t)b*NK*H + h0*16;
    for (int idx = tid; idx < NK*8; idx += 256){
        int key = idx >> 3, p = idx & 7;
        int hh = p >> 2, dl = (p & 3)*4;
        const uint_t* src = (const uint_t*)(Kb + (size_t)key*H + hh*16 + dl);
        uint_t* d = (uint_t*)&Ks[hh][key][dl];
        d[0] = src[0]; d[1] = src[1];
    }
    // stage V transposed
    const ushort_t* Vb = V + (size_t)b*NK*H + h0*16;
    for (int idx = tid; idx < NK*8; idx += 256){
        int key = idx >> 3, p = idx & 7;
        int hh = p >> 2, dl = (p & 3)*4;
        const ushort_t* src = Vb + (size_t)key*H + hh*16 + dl;
        Vs[hh][dl+0][key] = src[0];
        Vs[hh][dl+1][key] = src[1];
        Vs[hh][dl+2][key] = src[2];
        Vs[hh][dl+3][key] = src[3];
    }
    // zero V pad keys [NK,232)
    for (int idx = tid; idx < 2*16*(232-NK); idx += 256){
        int key = NK + idx % (232-NK), r = idx / (232-NK);
        Vs[r>>4][r&15][key] = 0;
    }
    __syncthreads();

    int w = tid >> 6, lane = tid & 63;
    int hh = w >> 1, half = w & 1;
    int h = h0 + hh;
    int l15 = lane & 15, quad = lane >> 4;
    bool klow = (quad < 2);
    int nqt = (nq + 15) >> 4;
    int split = (nqt + 1) >> 1;
    int qt0 = half ? split : 0;
    int qt1 = half ? nqt : split;
    for (int qt = qt0; qt < qt1; ++qt){
        // A frag: Q rows (clamped), d = quad*8.. ; zero for k>=16
        int qr = qt*16 + l15; if (qr > nq-1) qr = nq-1;
        short8 av = *(const short8*)(Q + (size_t)b*qbs + (size_t)qr*H + h*16 + (quad & 1)*8);
        short8 zero8 = (short8)0;
        short8 afrag = klow ? av : zero8;
        float4v s[NKT];
        #pragma unroll
        for (int kt = 0; kt < NKT; ++kt){
            short8 bv = *(const short8*)(&Ks[hh][kt*16 + l15][(quad & 1)*8]);
            short8 bfrag = klow ? bv : zero8;
            s[kt] = __builtin_amdgcn_mfma_f32_16x16x32_bf16(afrag, bfrag, (float4v)0.f, 0, 0, 0);
        }
        // mask invalid keys, row max
        float mx[4] = {-1e30f, -1e30f, -1e30f, -1e30f};
        #pragma unroll
        for (int kt = 0; kt < NKT; ++kt){
            if (kt*16 + l15 >= NK){ s[kt][0]=-1e30f; s[kt][1]=-1e30f; s[kt][2]=-1e30f; s[kt][3]=-1e30f; }
            #pragma unroll
            for (int r = 0; r < 4; ++r) mx[r] = fmaxf(mx[r], s[kt][r]);
        }
        #pragma unroll
        for (int off = 1; off < 16; off <<= 1){
            #pragma unroll
            for (int r = 0; r < 4; ++r) mx[r] = fmaxf(mx[r], __shfl_xor(mx[r], off));
        }
        // exp, sum, P -> LDS (A-layout)
        float sum[4] = {0.f, 0.f, 0.f, 0.f};
        #pragma unroll
        for (int kt = 0; kt < NKT; ++kt){
            #pragma unroll
            for (int r = 0; r < 4; ++r){
                float e = __expf((s[kt][r] - mx[r]) * SCALE);
                sum[r] += e;
                Ps[w][quad*4 + r][kt*16 + l15] = f2bf(e);
            }
        }
        #pragma unroll
        for (int off = 1; off < 16; off <<= 1){
            #pragma unroll
            for (int r = 0; r < 4; ++r) sum[r] += __shfl_xor(sum[r], off);
        }
        // PV
        float4v o = (float4v)0.f;
        #pragma unroll
        for (int kc = 0; kc < NKC; ++kc){
            short8 pa = *(const short8*)(&Ps[w][l15][kc*32 + quad*8]);
            short8 vb = *(const short8*)(&Vs[hh][l15][kc*32 + quad*8]);
            o = __builtin_amdgcn_mfma_f32_16x16x32_bf16(pa, vb, o, 0, 0, 0);
        }
        // store: row = qt*16 + quad*4 + r, col = h*16 + l15
        #pragma unroll
        for (int r = 0; r < 4; ++r){
            int row = qt*16 + quad*4 + r;
            if (row < nq){
                float qv = bf2f(Q[(size_t)b*qbs + (size_t)row*H + h*16 + l15]);
                out[((size_t)b*nq + row)*H + h*16 + l15] = f2bf(qv + o[r] / sum[r]);
            }
        }
    }
}

// ---------------- hERG (fp32) ----------------
__global__ void k_herg(const float* __restrict__ em, const float* __restrict__ W,
                       const float* __restrict__ b, float* __restrict__ outv)
{
    __shared__ float e[1280];
    int t = threadIdx.x;
    for (int i = t; i < 1280; i += 128) e[i] = em[i];
    __syncthreads();
    float acc = 0.f;
    for (int k = 0; k < 1280; ++k) acc += e[k] * W[(size_t)t*1280 + k];
    outv[t] = fmaxf(acc + b[t], 0.f);
}

// ---------------- head MLP (fp32) ----------------
__global__ __launch_bounds__(128) void k_final(const float* __restrict__ lin2out,
    const float* __restrict__ hergv,
    const float* __restrict__ hoW, const float* __restrict__ hob,
    const float* __restrict__ fcW, const float* __restrict__ fcb,
    const float* __restrict__ sW,  const float* __restrict__ sb,
    float* __restrict__ outp)
{
    int b = blockIdx.x, t = threadIdx.x;
    __shared__ float v256[256];
    __shared__ float tt[128];
    __shared__ float red[128];
    v256[t]       = lin2out[(size_t)b*H + t];
    v256[128 + t] = hergv[t];
    __syncthreads();
    float acc = 0.f;
    for (int k = 0; k < 256; ++k) acc += v256[k] * hoW[(size_t)t*256 + k];
    tt[t] = fmaxf(acc + hob[t], 0.f);
    __syncthreads();
    acc = 0.f;
    for (int k = 0; k < 128; ++k) acc += tt[k] * fcW[(size_t)t*128 + k];
    float uv = fmaxf(acc + fcb[t], 0.f);
    red[t] = uv * sW[t];
    __syncthreads();
    for (int s = 64; s > 0; s >>= 1){
        if (t < s) red[t] += red[t + s];
        __syncthreads();
    }
    if (t == 0){
        float logit = red[0] + sb[0];
        outp[b] = 1.f / (1.f + expf(-logit));
    }
}

extern "C" void kernel_launch(void* const* d_in, const int* in_sizes, int n_in,
                              void* d_out, int out_size, void* d_ws, size_t ws_size,
                              hipStream_t stream)
{
    (void)in_sizes; (void)n_in; (void)out_size; (void)ws_size;
    const float* herg_em = (const float*)d_in[0];
    const float* x_in    = (const float*)d_in[1];
    const float* convW[4] = {(const float*)d_in[4], (const float*)d_in[6], (const float*)d_in[8], (const float*)d_in[10]};
    const float* convB[4] = {(const float*)d_in[5], (const float*)d_in[7], (const float*)d_in[9], (const float*)d_in[11]};
    const float* lin1W = (const float*)d_in[12]; const float* lin1b = (const float*)d_in[13];
    const float* lin2W = (const float*)d_in[14]; const float* lin2b = (const float*)d_in[15];
    const float* S1    = (const float*)d_in[16];
    const float* p1fqW = (const float*)d_in[17]; const float* p1fqb = (const float*)d_in[18];
    const float* p1kW  = (const float*)d_in[19]; const float* p1kb  = (const float*)d_in[20];
    const float* p1vW  = (const float*)d_in[21]; const float* p1vb  = (const float*)d_in[22];
    const float* p1foW = (const float*)d_in[23]; const float* p1fob = (const float*)d_in[24];
    const float* sfqW  = (const float*)d_in[25]; const float* sfqb  = (const float*)d_in[26];
    const float* skW   = (const float*)d_in[27]; const float* skb   = (const float*)d_in[28];
    const float* svW   = (const float*)d_in[29]; const float* svb   = (const float*)d_in[30];
    const float* sfoW  = (const float*)d_in[31]; const float* sfob  = (const float*)d_in[32];
    const float* p2fqW = (const float*)d_in[33]; const float* p2fqb = (const float*)d_in[34];
    const float* p2kW  = (const float*)d_in[35]; const float* p2kb  = (const float*)d_in[36];
    const float* p2vW  = (const float*)d_in[37]; const float* p2vb  = (const float*)d_in[38];
    const float* p2foW = (const float*)d_in[39]; const float* p2fob = (const float*)d_in[40];
    const float* S2    = (const float*)d_in[41];
    const float* hlW   = (const float*)d_in[42]; const float* hlb   = (const float*)d_in[43];
    const float* hoW   = (const float*)d_in[44]; const float* hob   = (const float*)d_in[45];
    const float* fcW   = (const float*)d_in[46]; const float* fcb   = (const float*)d_in[47];
    const float* sW    = (const float*)d_in[48]; const float* sb    = (const float*)d_in[49];
    const int*  ei    = (const int*)d_in[50];
    const int*  esrc  = ei;
    const int*  edst  = ei + NE;
    float* outp = (float*)d_out;

    // -------- workspace layout (byte offsets, 16B-aligned) --------
    char* WS = (char*)d_ws;
    int*   counts = (int*)(WS + 0);
    int*   cursor = (int*)(WS + 400384);
    int*   row_st = (int*)(WS + 800768);
    int*   bSums  = (int*)(WS + 1201152);
    int*   bOff   = (int*)(WS + 1203200);
    float* dinv   = (float*)(WS + 1205248);
    float* selfc  = (float*)(WS + 1605632);
    int*   srcs_s = (int*)(WS + 2005632);
    float* ce_s   = (float*)(WS + 3605632);
    ushort_t* wbf = (ushort_t*)(WS + 5205632); // 17*16384
    ushort_t* w0bf= (ushort_t*)(WS + 5762688);
    ushort_t* s1bf= (ushort_t*)(WS + 5779072);
    ushort_t* s2bf= (ushort_t*)(WS + 5798272);
    ushort_t* q0  = (ushort_t*)(WS + 5798528);
    ushort_t* q2  = (ushort_t*)(WS + 5817728);
    float* hergv  = (float*)(WS + 5817984);
    float* l2out  = (float*)(WS + 5818496);
    ushort_t* x37 = (ushort_t*)(WS + 6074496); // NN*64
    ushort_t* b0  = (ushort_t*)(WS + 18874496);// NN*128
    ushort_t* b1  = (ushort_t*)(WS + 44474496);
    ushort_t* b2  = (ushort_t*)(WS + 70074496);
    ushort_t* xA  = (ushort_t*)(WS + 95674496);   // 37504*128
    ushort_t* xB  = (ushort_t*)(WS + 105275520);
    ushort_t* xQ  = (ushort_t*)(WS + 114876544);
    ushort_t* xK  = (ushort_t*)(WS + 124477568);
    ushort_t* xV  = (ushort_t*)(WS + 134078592);

    const int gN   = (NN + 255)/256;       // 391
    const int gE   = (NE + 255)/256;       // 1563
    const int gG   = (NN*64)/256;          // 25000
    const int gRow = (NN + 63)/64;         // 1563
    const int gXb  = (NB*NS + 63)/64;      // 586

    // ---- CSR build ----
    k_zero_i<<<gN, 256, 0, stream>>>(counts, NN);
    k_hist  <<<gE, 256, 0, stream>>>(counts, edst, NE);
    k_norms <<<gN, 256, 0, stream>>>(counts, dinv, selfc, NN);
    k_scan1 <<<gN, 256, 0, stream>>>(counts, row_st, bSums, NN);
    k_scan2 <<<1, 512, 0, stream>>>(bSums, bOff, gN);
    k_scan3 <<<gN, 256, 0, stream>>>(row_st, cursor, bOff, NN, NE);
    k_fillcsr<<<gE, 256, 0, stream>>>(esrc, edst, dinv, cursor, srcs_s, ce_s, NE);

    // ---- weight conversions ----
    WPtrs wp;
    wp.p[0]=convW[1]; wp.p[1]=convW[2]; wp.p[2]=convW[3]; wp.p[3]=lin1W; wp.p[4]=lin2W;
    wp.p[5]=p1kW; wp.p[6]=p1vW; wp.p[7]=p1foW;
    wp.p[8]=sfqW; wp.p[9]=skW; wp.p[10]=svW; wp.p[11]=sfoW;
    wp.p[12]=p2kW; wp.p[13]=p2vW; wp.p[14]=p2foW; wp.p[15]=p1fqW; wp.p[16]=p2fqW;
    k_cvtW <<<17*64, 256, 0, stream>>>(wp, wbf);
    k_cvtW0<<<32, 256, 0, stream>>>(convW[0], w0bf);
    k_cvt  <<<38, 256, 0, stream>>>(S1, s1bf, NS*H);
    k_cvt  <<<1, 256, 0, stream>>>(S2, s2bf, H);

    // ---- seed-Q projections + hERG ----
    gemm_mfma<<<2, 256, 0, stream>>>(s1bf, NS, H, wbf + (size_t)15*16384, p1fqb, q0, nullptr, 0, nullptr);
    gemm_mfma<<<1, 256, 0, stream>>>(s2bf, 1,  H, wbf + (size_t)16*16384, p2fqb, q2, nullptr, 0, nullptr);
    k_herg<<<1, 128, 0, stream>>>(herg_em, hlW, hlb, hergv);

    // ---- conv0: aggregate raw 37-dim, then MFMA GEMM (padded K=64) ----
    k_gather37b<<<gG, 256, 0, stream>>>(x_in, row_st, srcs_s, ce_s, selfc, x37, NN);
    gemm_mfma<<<gRow, 256, 0, stream>>>(x37, NN, 64, w0bf, convB[0], b0, nullptr, 1, nullptr);
    // ---- conv1..3: fused gather+GEMM (ping-pong b0<->b1) ----
    k_conv_fused<8><<<gRow, 256, 0, stream>>>(b0, row_st, srcs_s, ce_s, selfc,
        wbf + (size_t)0*16384, convB[1], nullptr, b1, nullptr, 1);
    k_conv_fused<8><<<gRow, 256, 0, stream>>>(b1, row_st, srcs_s, ce_s, selfc,
        wbf + (size_t)1*16384, convB[2], nullptr, b0, nullptr, 1);
    k_conv_fused<8><<<gRow, 256, 0, stream>>>(b0, row_st, srcs_s, ce_s, selfc,
        wbf + (size_t)2*16384, convB[3], nullptr, b1, nullptr, 1);
    // ---- lin1: hx -> b0 ----
    gemm_mfma<<<gRow, 256, 0, stream>>>(b1, NN, H, wbf + (size_t)3*16384, lin1b, b0, nullptr, 0, nullptr);
    // ---- pma1 K,V: fused shared-gather + dual GEMM (K->b1, V->b2) ----
    k_conv_fused<16><<<gRow, 256, 0, stream>>>(b0, row_st, srcs_s, ce_s, selfc,
        wbf + (size_t)5*16384, p1kb, p1vb, b1, b2, 0);
    // ---- GMPool_G attention ----
    k_attn_mfma<200><<<NB*4, 256, 0, stream>>>(q0, 0, b1, b2, xA, NS);
    gemm_mfma<<<gXb, 256, 0, stream>>>(xA, NB*NS, H, wbf + (size_t)7*16384, p1fob, xB, xA, 1, nullptr);
    // ---- SAB ----
    gemm_mfma<<<gXb, 256, 0, stream>>>(xB, NB*NS, H, wbf + (size_t)8*16384, sfqb, xQ, nullptr, 0, nullptr);
    gemm_mfma<<<gXb, 256, 0, stream>>>(xB, NB*NS, H, wbf + (size_t)9*16384, skb,  xK, nullptr, 0, nullptr);
    gemm_mfma<<<gXb, 256, 0, stream>>>(xB, NB*NS, H, wbf + (size_t)10*16384, svb, xV, nullptr, 0, nullptr);
    k_attn_mfma<75><<<NB*4, 256, 0, stream>>>(xQ, NS*H, xK, xV, xA, NS);
    gemm_mfma<<<gXb, 256, 0, stream>>>(xA, NB*NS, H, wbf + (size_t)11*16384, sfob, xB, xA, 1, nullptr);
    // ---- GMPool_I ----
    gemm_mfma<<<gXb, 256, 0, stream>>>(xB, NB*NS, H, wbf + (size_t)12*16384, p2kb, xK, nullptr, 0, nullptr);
    gemm_mfma<<<gXb, 256, 0, stream>>>(xB, NB*NS, H, wbf + (size_t)13*16384, p2vb, xV, nullptr, 0, nullptr);
    k_attn_mfma<75><<<NB*4, 256, 0, stream>>>(q2, 0, xK, xV, xA, 1);
    gemm_mfma<<<(NB+63)/64, 256, 0, stream>>>(xA, NB, H, wbf + (size_t)14*16384, p2fob, xB, xA, 1, nullptr);
    // ---- lin2 (fp32 out) ----
    gemm_mfma<<<(NB+63)/64, 256, 0, stream>>>(xB, NB, H, wbf + (size_t)4*16384, lin2b, nullptr, nullptr, 0, l2out);
    // ---- head ----
    k_final<<<NB, 128, 0, stream>>>(l2out, hergv, hoW, hob, fcW, fcb, sW, sb, outp);
}

// Round 7
// 976.778 us; speedup vs baseline: 6.3106x; 1.0515x over previous
//
#include <hip/hip_runtime.h>
#include <hip/hip_bf16.h>

typedef unsigned short ushort_t;
typedef unsigned int uint_t;
typedef __attribute__((ext_vector_type(8))) short short8;
typedef __attribute__((ext_vector_type(4))) float float4v;

static constexpr int NN  = 100000;   // nodes
static constexpr int NE  = 400000;   // edges
static constexpr int NB  = 500;      // graphs
static constexpr int NS  = 75;       // seeds
static constexpr int H   = 128;
static constexpr float SCALE = 0.08838834764831845f; // 1/sqrt(128)

union U32 { uint_t u; float f; };
__device__ __forceinline__ float bf2f(ushort_t b){ U32 t; t.u = ((uint_t)b) << 16; return t.f; }
__device__ __forceinline__ ushort_t f2bf(float f){
    U32 t; t.f = f;
    uint_t r = t.u + 0x7fffu + ((t.u >> 16) & 1u);   // RNE
    return (ushort_t)(r >> 16);
}
__device__ __forceinline__ void fma8(float* a, uint4 u, float c){
    a[0] += c * bf2f((ushort_t)(u.x & 0xffff)); a[1] += c * bf2f((ushort_t)(u.x >> 16));
    a[2] += c * bf2f((ushort_t)(u.y & 0xffff)); a[3] += c * bf2f((ushort_t)(u.y >> 16));
    a[4] += c * bf2f((ushort_t)(u.z & 0xffff)); a[5] += c * bf2f((ushort_t)(u.z >> 16));
    a[6] += c * bf2f((ushort_t)(u.w & 0xffff)); a[7] += c * bf2f((ushort_t)(u.w >> 16));
}

// ================= CSR build =================
__global__ void k_zero_i(int* __restrict__ p, int n){
    int i = blockIdx.x*256 + threadIdx.x;
    if (i < n) p[i] = 0;
}
__global__ void k_hist(int* counts, const int* __restrict__ dst, int e){
    int i = blockIdx.x*256 + threadIdx.x;
    if (i < e) atomicAdd(&counts[dst[i]], 1);
}
__global__ void k_norms(const int* __restrict__ counts, float* __restrict__ dinv,
                        float* __restrict__ selfc, int n){
    int i = blockIdx.x*256 + threadIdx.x;
    if (i < n){
        float r = rsqrtf(1.f + (float)counts[i]);
        dinv[i] = r; selfc[i] = r*r;
    }
}
__global__ __launch_bounds__(256) void k_scan1(const int* __restrict__ counts,
    int* __restrict__ row_start, int* __restrict__ blockSums, int n){
    __shared__ int s[256];
    int t = threadIdx.x, i = blockIdx.x*256 + t;
    int v = (i < n) ? counts[i] : 0;
    s[t] = v; __syncthreads();
    #pragma unroll
    for (int off = 1; off < 256; off <<= 1){
        int add = (t >= off) ? s[t-off] : 0;
        __syncthreads();
        s[t] += add;
        __syncthreads();
    }
    if (i < n) row_start[i] = s[t] - v;
    if (t == 255) blockSums[blockIdx.x] = s[255];
}
__global__ __launch_bounds__(512) void k_scan2(const int* __restrict__ blockSums,
    int* __restrict__ blockOff, int nb){
    __shared__ int s[512];
    int t = threadIdx.x;
    int v = (t < nb) ? blockSums[t] : 0;
    s[t] = v; __syncthreads();
    #pragma unroll
    for (int off = 1; off < 512; off <<= 1){
        int add = (t >= off) ? s[t-off] : 0;
        __syncthreads();
        s[t] += add;
        __syncthreads();
    }
    blockOff[t] = s[t] - v;
}
__global__ void k_scan3(int* __restrict__ row_start, int* __restrict__ cursor,
                        const int* __restrict__ blockOff, int n, int total){
    int i = blockIdx.x*256 + threadIdx.x;
    if (i < n){
        int v = row_start[i] + blockOff[i >> 8];
        row_start[i] = v; cursor[i] = v;
    }
    if (i == 0) row_start[n] = total;
}
__global__ void k_fillcsr(const int* __restrict__ src, const int* __restrict__ dst,
    const float* __restrict__ dinv, int* cursor,
    int* __restrict__ srcs_s, float* __restrict__ ce_s, int e){
    int i = blockIdx.x*256 + threadIdx.x;
    if (i < e){
        int d = dst[i], s = src[i];
        int p = atomicAdd(&cursor[d], 1);
        srcs_s[p] = s;
        ce_s[p] = dinv[s] * dinv[d];
    }
}

// ================= weight conversion =================
struct WPtrs { const float* p[17]; };
__global__ void k_cvtW(WPtrs wp, ushort_t* __restrict__ dst){
    int i = blockIdx.x*256 + threadIdx.x;   // 17*16384 total
    int idx = i >> 14, off = i & 16383;
    dst[i] = f2bf(wp.p[idx][off]);
}
__global__ void k_cvtW0(const float* __restrict__ src, ushort_t* __restrict__ dst){
    int i = blockIdx.x*256 + threadIdx.x;   // 128*64
    int r = i >> 6, c = i & 63;
    dst[i] = (c < 37) ? f2bf(src[r*37 + c]) : (ushort_t)0;
}
__global__ void k_cvt(const float* __restrict__ s, ushort_t* __restrict__ d, int n){
    int i = blockIdx.x*256 + threadIdx.x;
    if (i < n) d[i] = f2bf(s[i]);
}

// ========== MFMA GEMM: out[M,128] = resid + act(x[M,Ks] @ W[128,Ks]^T + b) ==========
__global__ __launch_bounds__(256) void gemm_mfma(
    const ushort_t* __restrict__ x, int M, int Ks,
    const ushort_t* __restrict__ W,
    const float* __restrict__ bias,
    ushort_t* out, const ushort_t* resid, int relu, float* out32)
{
    int tid  = threadIdx.x;
    int wid  = tid >> 6;
    int lane = tid & 63;
    int l15  = lane & 15, quad = lane >> 4;
    int row0 = blockIdx.x*64 + wid*16;
    int ar   = row0 + l15; if (ar > M-1) ar = M-1;
    const short* xr = (const short*)(x + (size_t)ar*Ks) + quad*8;
    float4v acc[8];
    #pragma unroll
    for (int i = 0; i < 8; ++i) acc[i] = (float4v)0.f;
    for (int k0 = 0; k0 < Ks; k0 += 32){
        short8 a = *(const short8*)(xr + k0);
        #pragma unroll
        for (int nt = 0; nt < 8; ++nt){
            const short* wr = (const short*)(W + (size_t)(nt*16 + l15)*Ks) + k0 + quad*8;
            short8 b = *(const short8*)wr;
            acc[nt] = __builtin_amdgcn_mfma_f32_16x16x32_bf16(a, b, acc[nt], 0, 0, 0);
        }
    }
    #pragma unroll
    for (int nt = 0; nt < 8; ++nt){
        int c = nt*16 + l15;
        float bv = bias ? bias[c] : 0.f;
        #pragma unroll
        for (int reg = 0; reg < 4; ++reg){
            int r = row0 + quad*4 + reg;
            if (r >= M) continue;
            float v = acc[nt][reg] + bv;
            if (relu) v = fmaxf(v, 0.f);
            if (resid) v += bf2f(resid[(size_t)r*H + c]);
            if (out32) out32[(size_t)r*H + c] = v;
            else       out[(size_t)r*H + c] = f2bf(v);
        }
    }
}

// ========== fused gather + MFMA GEMM v2 ==========
// 64 nodes/block, 4 threads/node (32 cols each). uint4 gather loads, x2-unrolled
// edge loop, LDS-staged coalesced uint4 stores.
// NOUT=8: one output. NOUT=16: W[256][128]; nt<8 -> out0, nt>=8 -> out1.
// STAGE2 (NOUT=8 only): second GEMM vs W2/bias2 applied to act(conv out); writes only final.
template<int NOUT, int RELU, int STAGE2>
__global__ __launch_bounds__(256) void k_conv_fused2(
    const ushort_t* __restrict__ x,
    const int* __restrict__ row_st, const int* __restrict__ srcs,
    const float* __restrict__ ces, const float* __restrict__ selfc,
    const ushort_t* __restrict__ W, const float* __restrict__ bias0,
    const float* __restrict__ bias1,
    const ushort_t* __restrict__ W2, const float* __restrict__ bias2,
    ushort_t* __restrict__ out0, ushort_t* __restrict__ out1)
{
    __shared__ ushort_t As[64][136];
    const int tid = threadIdx.x;
    const int node = tid >> 2, qq = tid & 3;
    const int g = blockIdx.x*64 + node;
    float acc[32];
    #pragma unroll
    for (int i = 0; i < 32; ++i) acc[i] = 0.f;
    if (g < NN){
        const uint4* xr = (const uint4*)(x + (size_t)g*H + qq*32);
        float sc = selfc[g];
        uint4 u0 = xr[0], u1 = xr[1], u2 = xr[2], u3 = xr[3];
        fma8(acc+0,u0,sc); fma8(acc+8,u1,sc); fma8(acc+16,u2,sc); fma8(acc+24,u3,sc);
        int e = row_st[g], e1 = row_st[g+1];
        for (; e + 2 <= e1; e += 2){
            int sA = srcs[e], sB = srcs[e+1];
            float cA = ces[e], cB = ces[e+1];
            const uint4* pa = (const uint4*)(x + (size_t)sA*H + qq*32);
            const uint4* pb = (const uint4*)(x + (size_t)sB*H + qq*32);
            uint4 a0=pa[0], a1=pa[1], a2=pa[2], a3=pa[3];
            uint4 c0=pb[0], c1=pb[1], c2=pb[2], c3=pb[3];
            fma8(acc+0,a0,cA); fma8(acc+8,a1,cA); fma8(acc+16,a2,cA); fma8(acc+24,a3,cA);
            fma8(acc+0,c0,cB); fma8(acc+8,c1,cB); fma8(acc+16,c2,cB); fma8(acc+24,c3,cB);
        }
        if (e < e1){
            int sA = srcs[e]; float cA = ces[e];
            const uint4* pa = (const uint4*)(x + (size_t)sA*H + qq*32);
            uint4 a0=pa[0], a1=pa[1], a2=pa[2], a3=pa[3];
            fma8(acc+0,a0,cA); fma8(acc+8,a1,cA); fma8(acc+16,a2,cA); fma8(acc+24,a3,cA);
        }
    }
    {
        uint_t* dst = (uint_t*)&As[node][qq*32];
        #pragma unroll
        for (int i = 0; i < 16; ++i)
            dst[i] = (uint_t)f2bf(acc[2*i]) | ((uint_t)f2bf(acc[2*i+1]) << 16);
    }
    __syncthreads();
    const int w = tid >> 6, lane = tid & 63, l15 = lane & 15, quad = lane >> 4;
    float4v o[NOUT];
    #pragma unroll
    for (int nt = 0; nt < NOUT; ++nt) o[nt] = (float4v)0.f;
    #pragma unroll
    for (int kc = 0; kc < 4; ++kc){
        short8 a = *(const short8*)(&As[w*16 + l15][kc*32 + quad*8]);
        #pragma unroll
        for (int nt = 0; nt < NOUT; ++nt){
            short8 bfr = *(const short8*)(W + (size_t)(nt*16 + l15)*H + kc*32 + quad*8);
            o[nt] = __builtin_amdgcn_mfma_f32_16x16x32_bf16(a, bfr, o[nt], 0, 0, 0);
        }
    }
    __syncthreads();
    // stage first 128 cols (conv out) into LDS
    #pragma unroll
    for (int nt = 0; nt < 8; ++nt){
        int c = nt*16 + l15;
        float bv = bias0[c];
        #pragma unroll
        for (int r = 0; r < 4; ++r){
            float v = o[nt][r] + bv;
            if (RELU) v = fmaxf(v, 0.f);
            As[w*16 + quad*4 + r][c] = f2bf(v);
        }
    }
    __syncthreads();
    if (STAGE2){
        float4v o2[8];
        #pragma unroll
        for (int nt = 0; nt < 8; ++nt) o2[nt] = (float4v)0.f;
        #pragma unroll
        for (int kc = 0; kc < 4; ++kc){
            short8 a = *(const short8*)(&As[w*16 + l15][kc*32 + quad*8]);
            #pragma unroll
            for (int nt = 0; nt < 8; ++nt){
                short8 bfr = *(const short8*)(W2 + (size_t)(nt*16 + l15)*H + kc*32 + quad*8);
                o2[nt] = __builtin_amdgcn_mfma_f32_16x16x32_bf16(a, bfr, o2[nt], 0, 0, 0);
            }
        }
        __syncthreads();
        #pragma unroll
        for (int nt = 0; nt < 8; ++nt){
            int c = nt*16 + l15;
            float bv = bias2[c];
            #pragma unroll
            for (int r = 0; r < 4; ++r)
                As[w*16 + quad*4 + r][c] = f2bf(o2[nt][r] + bv);
        }
        __syncthreads();
    }
    if (g < NN){
        uint4* op = (uint4*)(out0 + (size_t)g*H + qq*32);
        const uint4* sp = (const uint4*)&As[node][qq*32];
        op[0]=sp[0]; op[1]=sp[1]; op[2]=sp[2]; op[3]=sp[3];
    }
    if (NOUT == 16){
        __syncthreads();
        #pragma unroll
        for (int nt = 8; nt < NOUT; ++nt){
            int c = (nt-8)*16 + l15;
            float bv = bias1[c];
            #pragma unroll
            for (int r = 0; r < 4; ++r){
                float v = o[nt][r] + bv;
                if (RELU) v = fmaxf(v, 0.f);
                As[w*16 + quad*4 + r][c] = f2bf(v);
            }
        }
        __syncthreads();
        if (g < NN){
            uint4* op = (uint4*)(out1 + (size_t)g*H + qq*32);
            const uint4* sp = (const uint4*)&As[node][qq*32];
            op[0]=sp[0]; op[1]=sp[1]; op[2]=sp[2]; op[3]=sp[3];
        }
    }
}

// ========== fused conv0: gather raw fp32 37-dim (padded 64) + MFMA GEMM ==========
__global__ __launch_bounds__(256) void k_conv0_fused(
    const float* __restrict__ x,    // [NN][37] fp32
    const int* __restrict__ row_st, const int* __restrict__ srcs,
    const float* __restrict__ ces, const float* __restrict__ selfc,
    const ushort_t* __restrict__ W,  // [128][64] bf16 (cols>=37 zero)
    const float* __restrict__ bias,
    ushort_t* __restrict__ out)
{
    __shared__ ushort_t As[64][136];
    const int tid = threadIdx.x;
    const int node = tid >> 2, qq = tid & 3;
    const int g = blockIdx.x*64 + node;
    float acc[16];
    #pragma unroll
    for (int i = 0; i < 16; ++i) acc[i] = 0.f;
    const int lim = 37 - qq*16;
    if (g < NN){
        const float* xr = x + (size_t)g*37 + qq*16;
        float sc = selfc[g];
        #pragma unroll
        for (int i = 0; i < 16; ++i) if (i < lim) acc[i] = sc * xr[i];
        int e = row_st[g], e1 = row_st[g+1];
        for (; e < e1; ++e){
            int s = srcs[e]; float c = ces[e];
            const float* sr = x + (size_t)s*37 + qq*16;
            #pragma unroll
            for (int i = 0; i < 16; ++i) if (i < lim) acc[i] += c * sr[i];
        }
    }
    {
        uint_t* dst = (uint_t*)&As[node][qq*16];
        #pragma unroll
        for (int i = 0; i < 8; ++i)
            dst[i] = (uint_t)f2bf(acc[2*i]) | ((uint_t)f2bf(acc[2*i+1]) << 16);
    }
    __syncthreads();
    const int w = tid >> 6, lane = tid & 63, l15 = lane & 15, quad = lane >> 4;
    float4v o[8];
    #pragma unroll
    for (int nt = 0; nt < 8; ++nt) o[nt] = (float4v)0.f;
    #pragma unroll
    for (int kc = 0; kc < 2; ++kc){
        short8 a = *(const short8*)(&As[w*16 + l15][kc*32 + quad*8]);
        #pragma unroll
        for (int nt = 0; nt < 8; ++nt){
            short8 bfr = *(const short8*)(W + (size_t)(nt*16 + l15)*64 + kc*32 + quad*8);
            o[nt] = __builtin_amdgcn_mfma_f32_16x16x32_bf16(a, bfr, o[nt], 0, 0, 0);
        }
    }
    __syncthreads();
    #pragma unroll
    for (int nt = 0; nt < 8; ++nt){
        int c = nt*16 + l15;
        float bv = bias[c];
        #pragma unroll
        for (int r = 0; r < 4; ++r)
            As[w*16 + quad*4 + r][c] = f2bf(fmaxf(o[nt][r] + bv, 0.f));
    }
    __syncthreads();
    if (g < NN){
        uint4* op = (uint4*)(out + (size_t)g*H + qq*32);
        const uint4* sp = (const uint4*)&As[node][qq*32];
        op[0]=sp[0]; op[1]=sp[1]; op[2]=sp[2]; op[3]=sp[3];
    }
}

// ========== MFMA flash attention (unchanged from r5) ==========
template<int NK>
__global__ __launch_bounds__(256) void k_attn_mfma(
    const ushort_t* __restrict__ Q, int qbs,
    const ushort_t* __restrict__ K, const ushort_t* __restrict__ V,
    ushort_t* __restrict__ out, int nq)
{
    constexpr int NKT = (NK + 15) / 16;
    constexpr int NKC = (NK + 31) / 32;
    __shared__ ushort_t Ks[2][208][24];
    __shared__ ushort_t Vs[2][16][232];
    __shared__ ushort_t Ps[4][16][232];
    int b = blockIdx.x >> 2, hp = blockIdx.x & 3;
    int h0 = hp*2;
    int tid = threadIdx.x;
    {
        uint_t* p = (uint_t*)&Ps[0][0][0];
        for (int i = tid; i < 4*16*232/2; i += 256) p[i] = 0;
    }
    const ushort_t* Kb = K + (size_t)b*NK*H + h0*16;
    for (int idx = tid; idx < NK*8; idx += 256){
        int key = idx >> 3, p = idx & 7;
        int hh = p >> 2, dl = (p & 3)*4;
        const uint_t* src = (const uint_t*)(Kb + (size_t)key*H + hh*16 + dl);
        uint_t* d = (uint_t*)&Ks[hh][key][dl];
        d[0] = src[0]; d[1] = src[1];
    }
    const ushort_t* Vb = V + (size_t)b*NK*H + h0*16;
    for (int idx = tid; idx < NK*8; idx += 256){
        int key = idx >> 3, p = idx & 7;
        int hh = p >> 2, dl = (p & 3)*4;
        const ushort_t* src = Vb + (size_t)key*H + hh*16 + dl;
        Vs[hh][dl+0][key] = src[0];
        Vs[hh][dl+1][key] = src[1];
        Vs[hh][dl+2][key] = src[2];
        Vs[hh][dl+3][key] = src[3];
    }
    for (int idx = tid; idx < 2*16*(232-NK); idx += 256){
        int key = NK + idx % (232-NK), r = idx / (232-NK);
        Vs[r>>4][r&15][key] = 0;
    }
    __syncthreads();

    int w = tid >> 6, lane = tid & 63;
    int hh = w >> 1, half = w & 1;
    int h = h0 + hh;
    int l15 = lane & 15, quad = lane >> 4;
    bool klow = (quad < 2);
    int nqt = (nq + 15) >> 4;
    int split = (nqt + 1) >> 1;
    int qt0 = half ? split : 0;
    int qt1 = half ? nqt : split;
    for (int qt = qt0; qt < qt1; ++qt){
        int qr = qt*16 + l15; if (qr > nq-1) qr = nq-1;
        short8 av = *(const short8*)(Q + (size_t)b*qbs + (size_t)qr*H + h*16 + (quad & 1)*8);
        short8 zero8 = (short8)0;
        short8 afrag = klow ? av : zero8;
        float4v s[NKT];
        #pragma unroll
        for (int kt = 0; kt < NKT; ++kt){
            short8 bv = *(const short8*)(&Ks[hh][kt*16 + l15][(quad & 1)*8]);
            short8 bfrag = klow ? bv : zero8;
            s[kt] = __builtin_amdgcn_mfma_f32_16x16x32_bf16(afrag, bfrag, (float4v)0.f, 0, 0, 0);
        }
        float mx[4] = {-1e30f, -1e30f, -1e30f, -1e30f};
        #pragma unroll
        for (int kt = 0; kt < NKT; ++kt){
            if (kt*16 + l15 >= NK){ s[kt][0]=-1e30f; s[kt][1]=-1e30f; s[kt][2]=-1e30f; s[kt][3]=-1e30f; }
            #pragma unroll
            for (int r = 0; r < 4; ++r) mx[r] = fmaxf(mx[r], s[kt][r]);
        }
        #pragma unroll
        for (int off = 1; off < 16; off <<= 1){
            #pragma unroll
            for (int r = 0; r < 4; ++r) mx[r] = fmaxf(mx[r], __shfl_xor(mx[r], off));
        }
        float sum[4] = {0.f, 0.f, 0.f, 0.f};
        #pragma unroll
        for (int kt = 0; kt < NKT; ++kt){
            #pragma unroll
            for (int r = 0; r < 4; ++r){
                float e = __expf((s[kt][r] - mx[r]) * SCALE);
                sum[r] += e;
                Ps[w][quad*4 + r][kt*16 + l15] = f2bf(e);
            }
        }
        #pragma unroll
        for (int off = 1; off < 16; off <<= 1){
            #pragma unroll
            for (int r = 0; r < 4; ++r) sum[r] += __shfl_xor(sum[r], off);
        }
        float4v o = (float4v)0.f;
        #pragma unroll
        for (int kc = 0; kc < NKC; ++kc){
            short8 pa = *(const short8*)(&Ps[w][l15][kc*32 + quad*8]);
            short8 vb = *(const short8*)(&Vs[hh][l15][kc*32 + quad*8]);
            o = __builtin_amdgcn_mfma_f32_16x16x32_bf16(pa, vb, o, 0, 0, 0);
        }
        #pragma unroll
        for (int r = 0; r < 4; ++r){
            int row = qt*16 + quad*4 + r;
            if (row < nq){
                float qv = bf2f(Q[(size_t)b*qbs + (size_t)row*H + h*16 + l15]);
                out[((size_t)b*nq + row)*H + h*16 + l15] = f2bf(qv + o[r] / sum[r]);
            }
        }
    }
}

// ---------------- hERG (fp32) ----------------
__global__ void k_herg(const float* __restrict__ em, const float* __restrict__ W,
                       const float* __restrict__ b, float* __restrict__ outv)
{
    __shared__ float e[1280];
    int t = threadIdx.x;
    for (int i = t; i < 1280; i += 128) e[i] = em[i];
    __syncthreads();
    float acc = 0.f;
    for (int k = 0; k < 1280; ++k) acc += e[k] * W[(size_t)t*1280 + k];
    outv[t] = fmaxf(acc + b[t], 0.f);
}

// ---------------- head MLP (fp32) ----------------
__global__ __launch_bounds__(128) void k_final(const float* __restrict__ lin2out,
    const float* __restrict__ hergv,
    const float* __restrict__ hoW, const float* __restrict__ hob,
    const float* __restrict__ fcW, const float* __restrict__ fcb,
    const float* __restrict__ sW,  const float* __restrict__ sb,
    float* __restrict__ outp)
{
    int b = blockIdx.x, t = threadIdx.x;
    __shared__ float v256[256];
    __shared__ float tt[128];
    __shared__ float red[128];
    v256[t]       = lin2out[(size_t)b*H + t];
    v256[128 + t] = hergv[t];
    __syncthreads();
    float acc = 0.f;
    for (int k = 0; k < 256; ++k) acc += v256[k] * hoW[(size_t)t*256 + k];
    tt[t] = fmaxf(acc + hob[t], 0.f);
    __syncthreads();
    acc = 0.f;
    for (int k = 0; k < 128; ++k) acc += tt[k] * fcW[(size_t)t*128 + k];
    float uv = fmaxf(acc + fcb[t], 0.f);
    red[t] = uv * sW[t];
    __syncthreads();
    for (int s = 64; s > 0; s >>= 1){
        if (t < s) red[t] += red[t + s];
        __syncthreads();
    }
    if (t == 0){
        float logit = red[0] + sb[0];
        outp[b] = 1.f / (1.f + expf(-logit));
    }
}

extern "C" void kernel_launch(void* const* d_in, const int* in_sizes, int n_in,
                              void* d_out, int out_size, void* d_ws, size_t ws_size,
                              hipStream_t stream)
{
    (void)in_sizes; (void)n_in; (void)out_size; (void)ws_size;
    const float* herg_em = (const float*)d_in[0];
    const float* x_in    = (const float*)d_in[1];
    const float* convW[4] = {(const float*)d_in[4], (const float*)d_in[6], (const float*)d_in[8], (const float*)d_in[10]};
    const float* convB[4] = {(const float*)d_in[5], (const float*)d_in[7], (const float*)d_in[9], (const float*)d_in[11]};
    const float* lin1W = (const float*)d_in[12]; const float* lin1b = (const float*)d_in[13];
    const float* lin2W = (const float*)d_in[14]; const float* lin2b = (const float*)d_in[15];
    const float* S1    = (const float*)d_in[16];
    const float* p1fqW = (const float*)d_in[17]; const float* p1fqb = (const float*)d_in[18];
    const float* p1kW  = (const float*)d_in[19]; const float* p1kb  = (const float*)d_in[20];
    const float* p1vW  = (const float*)d_in[21]; const float* p1vb  = (const float*)d_in[22];
    const float* p1foW = (const float*)d_in[23]; const float* p1fob = (const float*)d_in[24];
    const float* sfqW  = (const float*)d_in[25]; const float* sfqb  = (const float*)d_in[26];
    const float* skW   = (const float*)d_in[27]; const float* skb   = (const float*)d_in[28];
    const float* svW   = (const float*)d_in[29]; const float* svb   = (const float*)d_in[30];
    const float* sfoW  = (const float*)d_in[31]; const float* sfob  = (const float*)d_in[32];
    const float* p2fqW = (const float*)d_in[33]; const float* p2fqb = (const float*)d_in[34];
    const float* p2kW  = (const float*)d_in[35]; const float* p2kb  = (const float*)d_in[36];
    const float* p2vW  = (const float*)d_in[37]; const float* p2vb  = (const float*)d_in[38];
    const float* p2foW = (const float*)d_in[39]; const float* p2fob = (const float*)d_in[40];
    const float* S2    = (const float*)d_in[41];
    const float* hlW   = (const float*)d_in[42]; const float* hlb   = (const float*)d_in[43];
    const float* hoW   = (const float*)d_in[44]; const float* hob   = (const float*)d_in[45];
    const float* fcW   = (const float*)d_in[46]; const float* fcb   = (const float*)d_in[47];
    const float* sW    = (const float*)d_in[48]; const float* sb    = (const float*)d_in[49];
    const int*  ei    = (const int*)d_in[50];
    const int*  esrc  = ei;
    const int*  edst  = ei + NE;
    float* outp = (float*)d_out;

    // -------- workspace layout (byte offsets, 16B-aligned) --------
    char* WS = (char*)d_ws;
    int*   counts = (int*)(WS + 0);
    int*   cursor = (int*)(WS + 400384);
    int*   row_st = (int*)(WS + 800768);
    int*   bSums  = (int*)(WS + 1201152);
    int*   bOff   = (int*)(WS + 1203200);
    float* dinv   = (float*)(WS + 1205248);
    float* selfc  = (float*)(WS + 1605632);
    int*   srcs_s = (int*)(WS + 2005632);
    float* ce_s   = (float*)(WS + 3605632);
    ushort_t* wbf = (ushort_t*)(WS + 5205632); // 17*16384
    ushort_t* w0bf= (ushort_t*)(WS + 5762688);
    ushort_t* s1bf= (ushort_t*)(WS + 5779072);
    ushort_t* s2bf= (ushort_t*)(WS + 5798272);
    ushort_t* q0  = (ushort_t*)(WS + 5798528);
    ushort_t* q2  = (ushort_t*)(WS + 5817728);
    float* hergv  = (float*)(WS + 5817984);
    float* l2out  = (float*)(WS + 5818496);
    ushort_t* b0  = (ushort_t*)(WS + 18874496);// NN*128
    ushort_t* b1  = (ushort_t*)(WS + 44474496);
    ushort_t* b2  = (ushort_t*)(WS + 70074496);
    ushort_t* xA  = (ushort_t*)(WS + 95674496);   // 37504*128
    ushort_t* xB  = (ushort_t*)(WS + 105275520);
    ushort_t* xQ  = (ushort_t*)(WS + 114876544);
    ushort_t* xK  = (ushort_t*)(WS + 124477568);
    ushort_t* xV  = (ushort_t*)(WS + 134078592);

    const int gN   = (NN + 255)/256;       // 391
    const int gE   = (NE + 255)/256;       // 1563
    const int gRow = (NN + 63)/64;         // 1563
    const int gXb  = (NB*NS + 63)/64;      // 586

    // ---- CSR build ----
    k_zero_i<<<gN, 256, 0, stream>>>(counts, NN);
    k_hist  <<<gE, 256, 0, stream>>>(counts, edst, NE);
    k_norms <<<gN, 256, 0, stream>>>(counts, dinv, selfc, NN);
    k_scan1 <<<gN, 256, 0, stream>>>(counts, row_st, bSums, NN);
    k_scan2 <<<1, 512, 0, stream>>>(bSums, bOff, gN);
    k_scan3 <<<gN, 256, 0, stream>>>(row_st, cursor, bOff, NN, NE);
    k_fillcsr<<<gE, 256, 0, stream>>>(esrc, edst, dinv, cursor, srcs_s, ce_s, NE);

    // ---- weight conversions ----
    WPtrs wp;
    wp.p[0]=convW[1]; wp.p[1]=convW[2]; wp.p[2]=convW[3]; wp.p[3]=lin1W; wp.p[4]=lin2W;
    wp.p[5]=p1kW; wp.p[6]=p1vW; wp.p[7]=p1foW;
    wp.p[8]=sfqW; wp.p[9]=skW; wp.p[10]=svW; wp.p[11]=sfoW;
    wp.p[12]=p2kW; wp.p[13]=p2vW; wp.p[14]=p2foW; wp.p[15]=p1fqW; wp.p[16]=p2fqW;
    k_cvtW <<<17*64, 256, 0, stream>>>(wp, wbf);
    k_cvtW0<<<32, 256, 0, stream>>>(convW[0], w0bf);
    k_cvt  <<<38, 256, 0, stream>>>(S1, s1bf, NS*H);
    k_cvt  <<<1, 256, 0, stream>>>(S2, s2bf, H);

    // ---- seed-Q projections + hERG ----
    gemm_mfma<<<2, 256, 0, stream>>>(s1bf, NS, H, wbf + (size_t)15*16384, p1fqb, q0, nullptr, 0, nullptr);
    gemm_mfma<<<1, 256, 0, stream>>>(s2bf, 1,  H, wbf + (size_t)16*16384, p2fqb, q2, nullptr, 0, nullptr);
    k_herg<<<1, 128, 0, stream>>>(herg_em, hlW, hlb, hergv);

    // ---- conv0 (fused gather37 + GEMM) -> b0 ----
    k_conv0_fused<<<gRow, 256, 0, stream>>>(x_in, row_st, srcs_s, ce_s, selfc, w0bf, convB[0], b0);
    // ---- conv1, conv2 ----
    k_conv_fused2<8,1,0><<<gRow, 256, 0, stream>>>(b0, row_st, srcs_s, ce_s, selfc,
        wbf + (size_t)0*16384, convB[1], nullptr, nullptr, nullptr, b1, nullptr);
    k_conv_fused2<8,1,0><<<gRow, 256, 0, stream>>>(b1, row_st, srcs_s, ce_s, selfc,
        wbf + (size_t)1*16384, convB[2], nullptr, nullptr, nullptr, b0, nullptr);
    // ---- conv3 + lin1 fused -> hx in b1 ----
    k_conv_fused2<8,1,1><<<gRow, 256, 0, stream>>>(b0, row_st, srcs_s, ce_s, selfc,
        wbf + (size_t)2*16384, convB[3], nullptr, wbf + (size_t)3*16384, lin1b, b1, nullptr);
    // ---- pma1 K,V: fused shared-gather + dual GEMM (K->b2, V->b0) ----
    k_conv_fused2<16,0,0><<<gRow, 256, 0, stream>>>(b1, row_st, srcs_s, ce_s, selfc,
        wbf + (size_t)5*16384, p1kb, p1vb, nullptr, nullptr, b2, b0);
    // ---- GMPool_G attention ----
    k_attn_mfma<200><<<NB*4, 256, 0, stream>>>(q0, 0, b2, b0, xA, NS);
    gemm_mfma<<<gXb, 256, 0, stream>>>(xA, NB*NS, H, wbf + (size_t)7*16384, p1fob, xB, xA, 1, nullptr);
    // ---- SAB ----
    gemm_mfma<<<gXb, 256, 0, stream>>>(xB, NB*NS, H, wbf + (size_t)8*16384, sfqb, xQ, nullptr, 0, nullptr);
    gemm_mfma<<<gXb, 256, 0, stream>>>(xB, NB*NS, H, wbf + (size_t)9*16384, skb,  xK, nullptr, 0, nullptr);
    gemm_mfma<<<gXb, 256, 0, stream>>>(xB, NB*NS, H, wbf + (size_t)10*16384, svb, xV, nullptr, 0, nullptr);
    k_attn_mfma<75><<<NB*4, 256, 0, stream>>>(xQ, NS*H, xK, xV, xA, NS);
    gemm_mfma<<<gXb, 256, 0, stream>>>(xA, NB*NS, H, wbf + (size_t)11*16384, sfob, xB, xA, 1, nullptr);
    // ---- GMPool_I ----
    gemm_mfma<<<gXb, 256, 0, stream>>>(xB, NB*NS, H, wbf + (size_t)12*16384, p2kb, xK, nullptr, 0, nullptr);
    gemm_mfma<<<gXb, 256, 0, stream>>>(xB, NB*NS, H, wbf + (size_t)13*16384, p2vb, xV, nullptr, 0, nullptr);
    k_attn_mfma<75><<<NB*4, 256, 0, stream>>>(q2, 0, xK, xV, xA, 1);
    gemm_mfma<<<(NB+63)/64, 256, 0, stream>>>(xA, NB, H, wbf + (size_t)14*16384, p2fob, xB, xA, 1, nullptr);
    // ---- lin2 (fp32 out) ----
    gemm_mfma<<<(NB+63)/64, 256, 0, stream>>>(xB, NB, H, wbf + (size_t)4*16384, lin2b, nullptr, nullptr, 0, l2out);
    // ---- head ----
    k_final<<<NB, 128, 0, stream>>>(l2out, hergv, hoW, hob, fcW, fcb, sW, sb, outp);
}

// Round 8
// 907.316 us; speedup vs baseline: 6.7938x; 1.0766x over previous
//
#include <hip/hip_runtime.h>
#include <hip/hip_bf16.h>

typedef unsigned short ushort_t;
typedef unsigned int uint_t;
typedef __attribute__((ext_vector_type(8))) short short8;
typedef __attribute__((ext_vector_type(4))) float float4v;

static constexpr int NN  = 100000;   // nodes
static constexpr int NE  = 400000;   // edges
static constexpr int NB  = 500;      // graphs
static constexpr int NS  = 75;       // seeds
static constexpr int H   = 128;
static constexpr float SCALE = 0.08838834764831845f; // 1/sqrt(128)

union U32 { uint_t u; float f; };
__device__ __forceinline__ float bf2f(ushort_t b){ U32 t; t.u = ((uint_t)b) << 16; return t.f; }
__device__ __forceinline__ ushort_t f2bf(float f){
    U32 t; t.f = f;
    uint_t r = t.u + 0x7fffu + ((t.u >> 16) & 1u);   // RNE
    return (ushort_t)(r >> 16);
}
__device__ __forceinline__ void fma8(float* a, uint4 u, float c){
    a[0] += c * bf2f((ushort_t)(u.x & 0xffff)); a[1] += c * bf2f((ushort_t)(u.x >> 16));
    a[2] += c * bf2f((ushort_t)(u.y & 0xffff)); a[3] += c * bf2f((ushort_t)(u.y >> 16));
    a[4] += c * bf2f((ushort_t)(u.z & 0xffff)); a[5] += c * bf2f((ushort_t)(u.z >> 16));
    a[6] += c * bf2f((ushort_t)(u.w & 0xffff)); a[7] += c * bf2f((ushort_t)(u.w >> 16));
}

// ================= CSR build =================
__global__ void k_zero_i(int* __restrict__ p, int n){
    int i = blockIdx.x*256 + threadIdx.x;
    if (i < n) p[i] = 0;
}
__global__ void k_hist(int* counts, const int* __restrict__ dst, int e){
    int i = blockIdx.x*256 + threadIdx.x;
    if (i < e) atomicAdd(&counts[dst[i]], 1);
}
__global__ void k_norms(const int* __restrict__ counts, float* __restrict__ dinv,
                        float* __restrict__ selfc, int n){
    int i = blockIdx.x*256 + threadIdx.x;
    if (i < n){
        float r = rsqrtf(1.f + (float)counts[i]);
        dinv[i] = r; selfc[i] = r*r;
    }
}
__global__ __launch_bounds__(256) void k_scan1(const int* __restrict__ counts,
    int* __restrict__ row_start, int* __restrict__ blockSums, int n){
    __shared__ int s[256];
    int t = threadIdx.x, i = blockIdx.x*256 + t;
    int v = (i < n) ? counts[i] : 0;
    s[t] = v; __syncthreads();
    #pragma unroll
    for (int off = 1; off < 256; off <<= 1){
        int add = (t >= off) ? s[t-off] : 0;
        __syncthreads();
        s[t] += add;
        __syncthreads();
    }
    if (i < n) row_start[i] = s[t] - v;
    if (t == 255) blockSums[blockIdx.x] = s[255];
}
__global__ __launch_bounds__(512) void k_scan2(const int* __restrict__ blockSums,
    int* __restrict__ blockOff, int nb){
    __shared__ int s[512];
    int t = threadIdx.x;
    int v = (t < nb) ? blockSums[t] : 0;
    s[t] = v; __syncthreads();
    #pragma unroll
    for (int off = 1; off < 512; off <<= 1){
        int add = (t >= off) ? s[t-off] : 0;
        __syncthreads();
        s[t] += add;
        __syncthreads();
    }
    blockOff[t] = s[t] - v;
}
__global__ void k_scan3(int* __restrict__ row_start, int* __restrict__ cursor,
                        const int* __restrict__ blockOff, int n, int total){
    int i = blockIdx.x*256 + threadIdx.x;
    if (i < n){
        int v = row_start[i] + blockOff[i >> 8];
        row_start[i] = v; cursor[i] = v;
    }
    if (i == 0) row_start[n] = total;
}
__global__ void k_fillcsr(const int* __restrict__ src, const int* __restrict__ dst,
    const float* __restrict__ dinv, int* cursor,
    int* __restrict__ srcs_s, float* __restrict__ ce_s, int e){
    int i = blockIdx.x*256 + threadIdx.x;
    if (i < e){
        int d = dst[i], s = src[i];
        int p = atomicAdd(&cursor[d], 1);
        srcs_s[p] = s;
        ce_s[p] = dinv[s] * dinv[d];
    }
}

// ================= weight / input conversion =================
struct WPtrs { const float* p[17]; };
__global__ void k_cvtW(WPtrs wp, ushort_t* __restrict__ dst){
    int i = blockIdx.x*256 + threadIdx.x;   // 17*16384 total
    int idx = i >> 14, off = i & 16383;
    dst[i] = f2bf(wp.p[idx][off]);
}
__global__ void k_cvtW0(const float* __restrict__ src, ushort_t* __restrict__ dst){
    int i = blockIdx.x*256 + threadIdx.x;   // 128*64
    int r = i >> 6, c = i & 63;
    dst[i] = (c < 37) ? f2bf(src[r*37 + c]) : (ushort_t)0;
}
__global__ void k_cvt(const float* __restrict__ s, ushort_t* __restrict__ d, int n){
    int i = blockIdx.x*256 + threadIdx.x;
    if (i < n) d[i] = f2bf(s[i]);
}
// pad raw x[NN][37] fp32 -> [NN][64] bf16 (zeros beyond 37)
__global__ void k_cvt37(const float* __restrict__ x, ushort_t* __restrict__ xb, int n){
    int i = blockIdx.x*256 + threadIdx.x;
    if (i < n*64){
        int r = i >> 6, c = i & 63;
        xb[i] = (c < 37) ? f2bf(x[(size_t)r*37 + c]) : (ushort_t)0;
    }
}

// ========== MFMA GEMM: out[M,128] = resid + act(x[M,Ks] @ W[128,Ks]^T + b) ==========
__global__ __launch_bounds__(256) void gemm_mfma(
    const ushort_t* __restrict__ x, int M, int Ks,
    const ushort_t* __restrict__ W,
    const float* __restrict__ bias,
    ushort_t* out, const ushort_t* resid, int relu, float* out32)
{
    int tid  = threadIdx.x;
    int wid  = tid >> 6;
    int lane = tid & 63;
    int l15  = lane & 15, quad = lane >> 4;
    int row0 = blockIdx.x*64 + wid*16;
    int ar   = row0 + l15; if (ar > M-1) ar = M-1;
    const short* xr = (const short*)(x + (size_t)ar*Ks) + quad*8;
    float4v acc[8];
    #pragma unroll
    for (int i = 0; i < 8; ++i) acc[i] = (float4v)0.f;
    for (int k0 = 0; k0 < Ks; k0 += 32){
        short8 a = *(const short8*)(xr + k0);
        #pragma unroll
        for (int nt = 0; nt < 8; ++nt){
            const short* wr = (const short*)(W + (size_t)(nt*16 + l15)*Ks) + k0 + quad*8;
            short8 b = *(const short8*)wr;
            acc[nt] = __builtin_amdgcn_mfma_f32_16x16x32_bf16(a, b, acc[nt], 0, 0, 0);
        }
    }
    #pragma unroll
    for (int nt = 0; nt < 8; ++nt){
        int c = nt*16 + l15;
        float bv = bias ? bias[c] : 0.f;
        #pragma unroll
        for (int reg = 0; reg < 4; ++reg){
            int r = row0 + quad*4 + reg;
            if (r >= M) continue;
            float v = acc[nt][reg] + bv;
            if (relu) v = fmaxf(v, 0.f);
            if (resid) v += bf2f(resid[(size_t)r*H + c]);
            if (out32) out32[(size_t)r*H + c] = v;
            else       out[(size_t)r*H + c] = f2bf(v);
        }
    }
}

// ========== fused gather + MFMA GEMM v3: 32 nodes/block, 8 threads/node ==========
// MINW: min waves/EU (occupancy request). NOUT=8: one 128-col output.
// NOUT=16: W[256][128], waves 0-1 -> out0 cols, waves 2-3 -> out1 cols.
// STAGE2 (NOUT=8 only): second GEMM vs W2/bias2 on act(conv out).
template<int NOUT, int RELU, int STAGE2, int MINW>
__global__ __launch_bounds__(256, MINW) void k_conv_fused3(
    const ushort_t* __restrict__ x,
    const int* __restrict__ row_st, const int* __restrict__ srcs,
    const float* __restrict__ ces, const float* __restrict__ selfc,
    const ushort_t* __restrict__ W, const float* __restrict__ bias0,
    const float* __restrict__ bias1,
    const ushort_t* __restrict__ W2, const float* __restrict__ bias2,
    ushort_t* __restrict__ out0, ushort_t* __restrict__ out1)
{
    __shared__ ushort_t As[32][136];
    __shared__ ushort_t Bs[(NOUT==16)?32:1][(NOUT==16)?136:1];
    const int tid = threadIdx.x;
    const int node = tid >> 3, qq = tid & 7;   // 8 threads/node, 16 cols (2x uint4) each
    const int g = blockIdx.x*32 + node;
    float acc[16];
    #pragma unroll
    for (int i = 0; i < 16; ++i) acc[i] = 0.f;
    if (g < NN){
        const uint4* xr = (const uint4*)(x + (size_t)g*H + qq*16);
        float sc = selfc[g];
        uint4 u0 = xr[0], u1 = xr[1];
        fma8(acc+0, u0, sc); fma8(acc+8, u1, sc);
        int e = row_st[g], e1 = row_st[g+1];
        for (; e + 2 <= e1; e += 2){
            int sA = srcs[e], sB = srcs[e+1];
            float cA = ces[e], cB = ces[e+1];
            const uint4* pa = (const uint4*)(x + (size_t)sA*H + qq*16);
            const uint4* pb = (const uint4*)(x + (size_t)sB*H + qq*16);
            uint4 a0 = pa[0], a1 = pa[1];
            uint4 c0 = pb[0], c1 = pb[1];
            fma8(acc+0, a0, cA); fma8(acc+8, a1, cA);
            fma8(acc+0, c0, cB); fma8(acc+8, c1, cB);
        }
        if (e < e1){
            int sA = srcs[e]; float cA = ces[e];
            const uint4* pa = (const uint4*)(x + (size_t)sA*H + qq*16);
            uint4 a0 = pa[0], a1 = pa[1];
            fma8(acc+0, a0, cA); fma8(acc+8, a1, cA);
        }
    }
    {
        uint_t* dst = (uint_t*)&As[node][qq*16];
        #pragma unroll
        for (int i = 0; i < 8; ++i)
            dst[i] = (uint_t)f2bf(acc[2*i]) | ((uint_t)f2bf(acc[2*i+1]) << 16);
    }
    __syncthreads();
    const int w = tid >> 6, lane = tid & 63, l15 = lane & 15, quad = lane >> 4;
    const int rt = w & 1;                  // row tile (16 rows)
    constexpr int NT = NOUT/2;             // col tiles per wave
    const int ct0 = (w >> 1) * NT;
    float4v o[NT];
    #pragma unroll
    for (int t = 0; t < NT; ++t) o[t] = (float4v)0.f;
    #pragma unroll
    for (int kc = 0; kc < 4; ++kc){
        short8 a = *(const short8*)(&As[rt*16 + l15][kc*32 + quad*8]);
        #pragma unroll
        for (int t = 0; t < NT; ++t){
            short8 bfr = *(const short8*)(W + (size_t)((ct0 + t)*16 + l15)*H + kc*32 + quad*8);
            o[t] = __builtin_amdgcn_mfma_f32_16x16x32_bf16(a, bfr, o[t], 0, 0, 0);
        }
    }
    __syncthreads();
    #pragma unroll
    for (int t = 0; t < NT; ++t){
        int cg = (ct0 + t)*16 + l15;
        #pragma unroll
        for (int r = 0; r < 4; ++r){
            float v;
            if (NOUT == 8 || cg < 128){
                v = o[t][r] + bias0[cg];
                if (RELU) v = fmaxf(v, 0.f);
                As[rt*16 + quad*4 + r][cg] = f2bf(v);
            } else {
                v = o[t][r] + bias1[cg - 128];
                if (RELU) v = fmaxf(v, 0.f);
                Bs[rt*16 + quad*4 + r][cg - 128] = f2bf(v);
            }
        }
    }
    __syncthreads();
    if (STAGE2){
        float4v o2[4];
        #pragma unroll
        for (int t = 0; t < 4; ++t) o2[t] = (float4v)0.f;
        const int ct2 = (w >> 1) * 4;
        #pragma unroll
        for (int kc = 0; kc < 4; ++kc){
            short8 a = *(const short8*)(&As[rt*16 + l15][kc*32 + quad*8]);
            #pragma unroll
            for (int t = 0; t < 4; ++t){
                short8 bfr = *(const short8*)(W2 + (size_t)((ct2 + t)*16 + l15)*H + kc*32 + quad*8);
                o2[t] = __builtin_amdgcn_mfma_f32_16x16x32_bf16(a, bfr, o2[t], 0, 0, 0);
            }
        }
        __syncthreads();
        #pragma unroll
        for (int t = 0; t < 4; ++t){
            int cg = (ct2 + t)*16 + l15;
            #pragma unroll
            for (int r = 0; r < 4; ++r)
                As[rt*16 + quad*4 + r][cg] = f2bf(o2[t][r] + bias2[cg]);
        }
        __syncthreads();
    }
    if (g < NN){
        uint4* op = (uint4*)(out0 + (size_t)g*H + qq*16);
        const uint4* sp = (const uint4*)&As[node][qq*16];
        op[0] = sp[0]; op[1] = sp[1];
        if (NOUT == 16){
            uint4* oq = (uint4*)(out1 + (size_t)g*H + qq*16);
            const uint4* sq = (const uint4*)&Bs[node][qq*16];
            oq[0] = sq[0]; oq[1] = sq[1];
        }
    }
}

// ========== conv0: gather padded-64 bf16 rows + MFMA GEMM (K=64) ==========
__global__ __launch_bounds__(256, 8) void k_conv0b(
    const ushort_t* __restrict__ x,   // [NN][64] bf16
    const int* __restrict__ row_st, const int* __restrict__ srcs,
    const float* __restrict__ ces, const float* __restrict__ selfc,
    const ushort_t* __restrict__ W,   // [128][64]
    const float* __restrict__ bias,
    ushort_t* __restrict__ out)
{
    __shared__ ushort_t As[32][136];
    const int tid = threadIdx.x;
    const int node = tid >> 3, qq = tid & 7;   // 8 cols (1 uint4) each
    const int g = blockIdx.x*32 + node;
    float acc[8];
    #pragma unroll
    for (int i = 0; i < 8; ++i) acc[i] = 0.f;
    if (g < NN){
        const uint4* xr = (const uint4*)(x + (size_t)g*64 + qq*8);
        float sc = selfc[g];
        fma8(acc, xr[0], sc);
        int e = row_st[g], e1 = row_st[g+1];
        for (; e + 2 <= e1; e += 2){
            int sA = srcs[e], sB = srcs[e+1];
            float cA = ces[e], cB = ces[e+1];
            uint4 a0 = *(const uint4*)(x + (size_t)sA*64 + qq*8);
            uint4 c0 = *(const uint4*)(x + (size_t)sB*64 + qq*8);
            fma8(acc, a0, cA);
            fma8(acc, c0, cB);
        }
        if (e < e1){
            uint4 a0 = *(const uint4*)(x + (size_t)srcs[e]*64 + qq*8);
            fma8(acc, a0, ces[e]);
        }
    }
    {
        uint_t* dst = (uint_t*)&As[node][qq*8];
        #pragma unroll
        for (int i = 0; i < 4; ++i)
            dst[i] = (uint_t)f2bf(acc[2*i]) | ((uint_t)f2bf(acc[2*i+1]) << 16);
    }
    __syncthreads();
    const int w = tid >> 6, lane = tid & 63, l15 = lane & 15, quad = lane >> 4;
    const int rt = w & 1;
    const int ct0 = (w >> 1) * 4;
    float4v o[4];
    #pragma unroll
    for (int t = 0; t < 4; ++t) o[t] = (float4v)0.f;
    #pragma unroll
    for (int kc = 0; kc < 2; ++kc){
        short8 a = *(const short8*)(&As[rt*16 + l15][kc*32 + quad*8]);
        #pragma unroll
        for (int t = 0; t < 4; ++t){
            short8 bfr = *(const short8*)(W + (size_t)((ct0 + t)*16 + l15)*64 + kc*32 + quad*8);
            o[t] = __builtin_amdgcn_mfma_f32_16x16x32_bf16(a, bfr, o[t], 0, 0, 0);
        }
    }
    __syncthreads();
    #pragma unroll
    for (int t = 0; t < 4; ++t){
        int cg = (ct0 + t)*16 + l15;
        #pragma unroll
        for (int r = 0; r < 4; ++r)
            As[rt*16 + quad*4 + r][cg] = f2bf(fmaxf(o[t][r] + bias[cg], 0.f));
    }
    __syncthreads();
    if (g < NN){
        uint4* op = (uint4*)(out + (size_t)g*H + qq*16);
        const uint4* sp = (const uint4*)&As[node][qq*16];
        op[0] = sp[0]; op[1] = sp[1];
    }
}

// ========== MFMA flash attention (unchanged) ==========
template<int NK>
__global__ __launch_bounds__(256) void k_attn_mfma(
    const ushort_t* __restrict__ Q, int qbs,
    const ushort_t* __restrict__ K, const ushort_t* __restrict__ V,
    ushort_t* __restrict__ out, int nq)
{
    constexpr int NKT = (NK + 15) / 16;
    constexpr int NKC = (NK + 31) / 32;
    __shared__ ushort_t Ks[2][208][24];
    __shared__ ushort_t Vs[2][16][232];
    __shared__ ushort_t Ps[4][16][232];
    int b = blockIdx.x >> 2, hp = blockIdx.x & 3;
    int h0 = hp*2;
    int tid = threadIdx.x;
    {
        uint_t* p = (uint_t*)&Ps[0][0][0];
        for (int i = tid; i < 4*16*232/2; i += 256) p[i] = 0;
    }
    const ushort_t* Kb = K + (size_t)b*NK*H + h0*16;
    for (int idx = tid; idx < NK*8; idx += 256){
        int key = idx >> 3, p = idx & 7;
        int hh = p >> 2, dl = (p & 3)*4;
        const uint_t* src = (const uint_t*)(Kb + (size_t)key*H + hh*16 + dl);
        uint_t* d = (uint_t*)&Ks[hh][key][dl];
        d[0] = src[0]; d[1] = src[1];
    }
    const ushort_t* Vb = V + (size_t)b*NK*H + h0*16;
    for (int idx = tid; idx < NK*8; idx += 256){
        int key = idx >> 3, p = idx & 7;
        int hh = p >> 2, dl = (p & 3)*4;
        const ushort_t* src = Vb + (size_t)key*H + hh*16 + dl;
        Vs[hh][dl+0][key] = src[0];
        Vs[hh][dl+1][key] = src[1];
        Vs[hh][dl+2][key] = src[2];
        Vs[hh][dl+3][key] = src[3];
    }
    for (int idx = tid; idx < 2*16*(232-NK); idx += 256){
        int key = NK + idx % (232-NK), r = idx / (232-NK);
        Vs[r>>4][r&15][key] = 0;
    }
    __syncthreads();

    int w = tid >> 6, lane = tid & 63;
    int hh = w >> 1, half = w & 1;
    int h = h0 + hh;
    int l15 = lane & 15, quad = lane >> 4;
    bool klow = (quad < 2);
    int nqt = (nq + 15) >> 4;
    int split = (nqt + 1) >> 1;
    int qt0 = half ? split : 0;
    int qt1 = half ? nqt : split;
    for (int qt = qt0; qt < qt1; ++qt){
        int qr = qt*16 + l15; if (qr > nq-1) qr = nq-1;
        short8 av = *(const short8*)(Q + (size_t)b*qbs + (size_t)qr*H + h*16 + (quad & 1)*8);
        short8 zero8 = (short8)0;
        short8 afrag = klow ? av : zero8;
        float4v s[NKT];
        #pragma unroll
        for (int kt = 0; kt < NKT; ++kt){
            short8 bv = *(const short8*)(&Ks[hh][kt*16 + l15][(quad & 1)*8]);
            short8 bfrag = klow ? bv : zero8;
            s[kt] = __builtin_amdgcn_mfma_f32_16x16x32_bf16(afrag, bfrag, (float4v)0.f, 0, 0, 0);
        }
        float mx[4] = {-1e30f, -1e30f, -1e30f, -1e30f};
        #pragma unroll
        for (int kt = 0; kt < NKT; ++kt){
            if (kt*16 + l15 >= NK){ s[kt][0]=-1e30f; s[kt][1]=-1e30f; s[kt][2]=-1e30f; s[kt][3]=-1e30f; }
            #pragma unroll
            for (int r = 0; r < 4; ++r) mx[r] = fmaxf(mx[r], s[kt][r]);
        }
        #pragma unroll
        for (int off = 1; off < 16; off <<= 1){
            #pragma unroll
            for (int r = 0; r < 4; ++r) mx[r] = fmaxf(mx[r], __shfl_xor(mx[r], off));
        }
        float sum[4] = {0.f, 0.f, 0.f, 0.f};
        #pragma unroll
        for (int kt = 0; kt < NKT; ++kt){
            #pragma unroll
            for (int r = 0; r < 4; ++r){
                float e = __expf((s[kt][r] - mx[r]) * SCALE);
                sum[r] += e;
                Ps[w][quad*4 + r][kt*16 + l15] = f2bf(e);
            }
        }
        #pragma unroll
        for (int off = 1; off < 16; off <<= 1){
            #pragma unroll
            for (int r = 0; r < 4; ++r) sum[r] += __shfl_xor(sum[r], off);
        }
        float4v o = (float4v)0.f;
        #pragma unroll
        for (int kc = 0; kc < NKC; ++kc){
            short8 pa = *(const short8*)(&Ps[w][l15][kc*32 + quad*8]);
            short8 vb = *(const short8*)(&Vs[hh][l15][kc*32 + quad*8]);
            o = __builtin_amdgcn_mfma_f32_16x16x32_bf16(pa, vb, o, 0, 0, 0);
        }
        #pragma unroll
        for (int r = 0; r < 4; ++r){
            int row = qt*16 + quad*4 + r;
            if (row < nq){
                float qv = bf2f(Q[(size_t)b*qbs + (size_t)row*H + h*16 + l15]);
                out[((size_t)b*nq + row)*H + h*16 + l15] = f2bf(qv + o[r] / sum[r]);
            }
        }
    }
}

// ---------------- hERG (fp32) ----------------
__global__ void k_herg(const float* __restrict__ em, const float* __restrict__ W,
                       const float* __restrict__ b, float* __restrict__ outv)
{
    __shared__ float e[1280];
    int t = threadIdx.x;
    for (int i = t; i < 1280; i += 128) e[i] = em[i];
    __syncthreads();
    float acc = 0.f;
    for (int k = 0; k < 1280; ++k) acc += e[k] * W[(size_t)t*1280 + k];
    outv[t] = fmaxf(acc + b[t], 0.f);
}

// ---------------- head MLP (fp32) ----------------
__global__ __launch_bounds__(128) void k_final(const float* __restrict__ lin2out,
    const float* __restrict__ hergv,
    const float* __restrict__ hoW, const float* __restrict__ hob,
    const float* __restrict__ fcW, const float* __restrict__ fcb,
    const float* __restrict__ sW,  const float* __restrict__ sb,
    float* __restrict__ outp)
{
    int b = blockIdx.x, t = threadIdx.x;
    __shared__ float v256[256];
    __shared__ float tt[128];
    __shared__ float red[128];
    v256[t]       = lin2out[(size_t)b*H + t];
    v256[128 + t] = hergv[t];
    __syncthreads();
    float acc = 0.f;
    for (int k = 0; k < 256; ++k) acc += v256[k] * hoW[(size_t)t*256 + k];
    tt[t] = fmaxf(acc + hob[t], 0.f);
    __syncthreads();
    acc = 0.f;
    for (int k = 0; k < 128; ++k) acc += tt[k] * fcW[(size_t)t*128 + k];
    float uv = fmaxf(acc + fcb[t], 0.f);
    red[t] = uv * sW[t];
    __syncthreads();
    for (int s = 64; s > 0; s >>= 1){
        if (t < s) red[t] += red[t + s];
        __syncthreads();
    }
    if (t == 0){
        float logit = red[0] + sb[0];
        outp[b] = 1.f / (1.f + expf(-logit));
    }
}

extern "C" void kernel_launch(void* const* d_in, const int* in_sizes, int n_in,
                              void* d_out, int out_size, void* d_ws, size_t ws_size,
                              hipStream_t stream)
{
    (void)in_sizes; (void)n_in; (void)out_size; (void)ws_size;
    const float* herg_em = (const float*)d_in[0];
    const float* x_in    = (const float*)d_in[1];
    const float* convW[4] = {(const float*)d_in[4], (const float*)d_in[6], (const float*)d_in[8], (const float*)d_in[10]};
    const float* convB[4] = {(const float*)d_in[5], (const float*)d_in[7], (const float*)d_in[9], (const float*)d_in[11]};
    const float* lin1W = (const float*)d_in[12]; const float* lin1b = (const float*)d_in[13];
    const float* lin2W = (const float*)d_in[14]; const float* lin2b = (const float*)d_in[15];
    const float* S1    = (const float*)d_in[16];
    const float* p1fqW = (const float*)d_in[17]; const float* p1fqb = (const float*)d_in[18];
    const float* p1kW  = (const float*)d_in[19]; const float* p1kb  = (const float*)d_in[20];
    const float* p1vW  = (const float*)d_in[21]; const float* p1vb  = (const float*)d_in[22];
    const float* p1foW = (const float*)d_in[23]; const float* p1fob = (const float*)d_in[24];
    const float* sfqW  = (const float*)d_in[25]; const float* sfqb  = (const float*)d_in[26];
    const float* skW   = (const float*)d_in[27]; const float* skb   = (const float*)d_in[28];
    const float* svW   = (const float*)d_in[29]; const float* svb   = (const float*)d_in[30];
    const float* sfoW  = (const float*)d_in[31]; const float* sfob  = (const float*)d_in[32];
    const float* p2fqW = (const float*)d_in[33]; const float* p2fqb = (const float*)d_in[34];
    const float* p2kW  = (const float*)d_in[35]; const float* p2kb  = (const float*)d_in[36];
    const float* p2vW  = (const float*)d_in[37]; const float* p2vb  = (const float*)d_in[38];
    const float* p2foW = (const float*)d_in[39]; const float* p2fob = (const float*)d_in[40];
    const float* S2    = (const float*)d_in[41];
    const float* hlW   = (const float*)d_in[42]; const float* hlb   = (const float*)d_in[43];
    const float* hoW   = (const float*)d_in[44]; const float* hob   = (const float*)d_in[45];
    const float* fcW   = (const float*)d_in[46]; const float* fcb   = (const float*)d_in[47];
    const float* sW    = (const float*)d_in[48]; const float* sb    = (const float*)d_in[49];
    const int*  ei    = (const int*)d_in[50];
    const int*  esrc  = ei;
    const int*  edst  = ei + NE;
    float* outp = (float*)d_out;

    // -------- workspace layout (byte offsets, 16B-aligned) --------
    char* WS = (char*)d_ws;
    int*   counts = (int*)(WS + 0);
    int*   cursor = (int*)(WS + 400384);
    int*   row_st = (int*)(WS + 800768);
    int*   bSums  = (int*)(WS + 1201152);
    int*   bOff   = (int*)(WS + 1203200);
    float* dinv   = (float*)(WS + 1205248);
    float* selfc  = (float*)(WS + 1605632);
    int*   srcs_s = (int*)(WS + 2005632);
    float* ce_s   = (float*)(WS + 3605632);
    ushort_t* wbf = (ushort_t*)(WS + 5205632); // 17*16384
    ushort_t* w0bf= (ushort_t*)(WS + 5762688);
    ushort_t* s1bf= (ushort_t*)(WS + 5779072);
    ushort_t* s2bf= (ushort_t*)(WS + 5798272);
    ushort_t* q0  = (ushort_t*)(WS + 5798528);
    ushort_t* q2  = (ushort_t*)(WS + 5817728);
    float* hergv  = (float*)(WS + 5817984);
    float* l2out  = (float*)(WS + 5818496);
    ushort_t* xb64= (ushort_t*)(WS + 6074496); // NN*64 bf16 padded raw x
    ushort_t* b0  = (ushort_t*)(WS + 18874496);// NN*128
    ushort_t* b1  = (ushort_t*)(WS + 44474496);
    ushort_t* b2  = (ushort_t*)(WS + 70074496);
    ushort_t* xA  = (ushort_t*)(WS + 95674496);   // 37504*128
    ushort_t* xB  = (ushort_t*)(WS + 105275520);
    ushort_t* xQ  = (ushort_t*)(WS + 114876544);
    ushort_t* xK  = (ushort_t*)(WS + 124477568);
    ushort_t* xV  = (ushort_t*)(WS + 134078592);

    const int gN   = (NN + 255)/256;       // 391
    const int gE   = (NE + 255)/256;       // 1563
    const int gC   = (NN + 31)/32;         // 3125 (fused conv blocks)
    const int gXb  = (NB*NS + 63)/64;      // 586

    // ---- CSR build ----
    k_zero_i<<<gN, 256, 0, stream>>>(counts, NN);
    k_hist  <<<gE, 256, 0, stream>>>(counts, edst, NE);
    k_norms <<<gN, 256, 0, stream>>>(counts, dinv, selfc, NN);
    k_scan1 <<<gN, 256, 0, stream>>>(counts, row_st, bSums, NN);
    k_scan2 <<<1, 512, 0, stream>>>(bSums, bOff, gN);
    k_scan3 <<<gN, 256, 0, stream>>>(row_st, cursor, bOff, NN, NE);
    k_fillcsr<<<gE, 256, 0, stream>>>(esrc, edst, dinv, cursor, srcs_s, ce_s, NE);

    // ---- weight / input conversions ----
    WPtrs wp;
    wp.p[0]=convW[1]; wp.p[1]=convW[2]; wp.p[2]=convW[3]; wp.p[3]=lin1W; wp.p[4]=lin2W;
    wp.p[5]=p1kW; wp.p[6]=p1vW; wp.p[7]=p1foW;
    wp.p[8]=sfqW; wp.p[9]=skW; wp.p[10]=svW; wp.p[11]=sfoW;
    wp.p[12]=p2kW; wp.p[13]=p2vW; wp.p[14]=p2foW; wp.p[15]=p1fqW; wp.p[16]=p2fqW;
    k_cvtW <<<17*64, 256, 0, stream>>>(wp, wbf);
    k_cvtW0<<<32, 256, 0, stream>>>(convW[0], w0bf);
    k_cvt  <<<38, 256, 0, stream>>>(S1, s1bf, NS*H);
    k_cvt  <<<1, 256, 0, stream>>>(S2, s2bf, H);
    k_cvt37<<<(NN*64 + 255)/256, 256, 0, stream>>>(x_in, xb64, NN);

    // ---- seed-Q projections + hERG ----
    gemm_mfma<<<2, 256, 0, stream>>>(s1bf, NS, H, wbf + (size_t)15*16384, p1fqb, q0, nullptr, 0, nullptr);
    gemm_mfma<<<1, 256, 0, stream>>>(s2bf, 1,  H, wbf + (size_t)16*16384, p2fqb, q2, nullptr, 0, nullptr);
    k_herg<<<1, 128, 0, stream>>>(herg_em, hlW, hlb, hergv);

    // ---- conv0 (fused gather64 + GEMM) -> b0 ----
    k_conv0b<<<gC, 256, 0, stream>>>(xb64, row_st, srcs_s, ce_s, selfc, w0bf, convB[0], b0);
    // ---- conv1, conv2 ----
    k_conv_fused3<8,1,0,8><<<gC, 256, 0, stream>>>(b0, row_st, srcs_s, ce_s, selfc,
        wbf + (size_t)0*16384, convB[1], nullptr, nullptr, nullptr, b1, nullptr);
    k_conv_fused3<8,1,0,8><<<gC, 256, 0, stream>>>(b1, row_st, srcs_s, ce_s, selfc,
        wbf + (size_t)1*16384, convB[2], nullptr, nullptr, nullptr, b0, nullptr);
    // ---- conv3 + lin1 fused -> hx in b1 ----
    k_conv_fused3<8,1,1,8><<<gC, 256, 0, stream>>>(b0, row_st, srcs_s, ce_s, selfc,
        wbf + (size_t)2*16384, convB[3], nullptr, wbf + (size_t)3*16384, lin1b, b1, nullptr);
    // ---- pma1 K,V: fused shared-gather + dual GEMM (K->b2, V->b0) ----
    k_conv_fused3<16,0,0,4><<<gC, 256, 0, stream>>>(b1, row_st, srcs_s, ce_s, selfc,
        wbf + (size_t)5*16384, p1kb, p1vb, nullptr, nullptr, b2, b0);
    // ---- GMPool_G attention ----
    k_attn_mfma<200><<<NB*4, 256, 0, stream>>>(q0, 0, b2, b0, xA, NS);
    gemm_mfma<<<gXb, 256, 0, stream>>>(xA, NB*NS, H, wbf + (size_t)7*16384, p1fob, xB, xA, 1, nullptr);
    // ---- SAB ----
    gemm_mfma<<<gXb, 256, 0, stream>>>(xB, NB*NS, H, wbf + (size_t)8*16384, sfqb, xQ, nullptr, 0, nullptr);
    gemm_mfma<<<gXb, 256, 0, stream>>>(xB, NB*NS, H, wbf + (size_t)9*16384, skb,  xK, nullptr, 0, nullptr);
    gemm_mfma<<<gXb, 256, 0, stream>>>(xB, NB*NS, H, wbf + (size_t)10*16384, svb, xV, nullptr, 0, nullptr);
    k_attn_mfma<75><<<NB*4, 256, 0, stream>>>(xQ, NS*H, xK, xV, xA, NS);
    gemm_mfma<<<gXb, 256, 0, stream>>>(xA, NB*NS, H, wbf + (size_t)11*16384, sfob, xB, xA, 1, nullptr);
    // ---- GMPool_I ----
    gemm_mfma<<<gXb, 256, 0, stream>>>(xB, NB*NS, H, wbf + (size_t)12*16384, p2kb, xK, nullptr, 0, nullptr);
    gemm_mfma<<<gXb, 256, 0, stream>>>(xB, NB*NS, H, wbf + (size_t)13*16384, p2vb, xV, nullptr, 0, nullptr);
    k_attn_mfma<75><<<NB*4, 256, 0, stream>>>(q2, 0, xK, xV, xA, 1);
    gemm_mfma<<<(NB+63)/64, 256, 0, stream>>>(xA, NB, H, wbf + (size_t)14*16384, p2fob, xB, xA, 1, nullptr);
    // ---- lin2 (fp32 out) ----
    gemm_mfma<<<(NB+63)/64, 256, 0, stream>>>(xB, NB, H, wbf + (size_t)4*16384, lin2b, nullptr, nullptr, 0, l2out);
    // ---- head ----
    k_final<<<NB, 128, 0, stream>>>(l2out, hergv, hoW, hob, fcW, fcb, sW, sb, outp);
}